// Round 1
// baseline (600.473 us; speedup 1.0000x reference)
//
#include <hip/hip_runtime.h>

// Problem constants (from reference)
#define NNODES 50000
#define NEDGES 800000
#define INDIM  256
#define HIDC   64
#define HEADS  4
static constexpr int ETOT = NEDGES + NNODES;  // edges + self loops

// ---------------------------------------------------------------------------
// edge_index element-width detection: reference declares int64 but harness may
// hand us int32. If int64 (values < 2^31), every odd 32-bit word is zero.
__global__ void detect_k(const unsigned* __restrict__ ei32, int* __restrict__ flag) {
    int is64 = 1;
    for (int i = 1; i < 256; i += 2)
        if (ei32[i] != 0u) { is64 = 0; break; }
    *flag = is64;
}

__device__ __forceinline__ int load_idx(const void* ei, int is64, size_t pos) {
    return is64 ? (int)((const long long*)ei)[pos] : ((const int*)ei)[pos];
}

// ---------------------------------------------------------------------------
// CSR build: histogram of dst, exclusive scan, scatter src ids
__global__ __launch_bounds__(256)
void hist_k(const void* __restrict__ ei, const int* __restrict__ flag,
            int* __restrict__ count) {
    int e = blockIdx.x * 256 + threadIdx.x;
    if (e >= ETOT) return;
    int is64 = *flag;
    int dst = (e < NEDGES) ? load_idx(ei, is64, (size_t)NEDGES + e) : (e - NEDGES);
    atomicAdd(&count[dst], 1);
}

__global__ __launch_bounds__(1024)
void scan_k(const int* __restrict__ count, int* __restrict__ rowptr, int n) {
    __shared__ int wsum[16];
    __shared__ int sh_carry;
    const int tid = threadIdx.x;
    const int lane = tid & 63;
    const int w = tid >> 6;
    if (tid == 0) sh_carry = 0;
    __syncthreads();
    for (int base = 0; base < n; base += 1024) {
        int i = base + tid;
        int v = (i < n) ? count[i] : 0;
        int x = v;
        #pragma unroll
        for (int dd = 1; dd < 64; dd <<= 1) {
            int y = __shfl_up(x, dd);
            if (lane >= dd) x += y;
        }
        if (lane == 63) wsum[w] = x;
        __syncthreads();
        int woff = 0, total = 0;
        #pragma unroll
        for (int j = 0; j < 16; ++j) {
            if (j < w) woff += wsum[j];
            total += wsum[j];
        }
        if (i < n) rowptr[i] = sh_carry + woff + x - v;
        __syncthreads();
        if (tid == 0) sh_carry += total;
        __syncthreads();
    }
    if (tid == 0) rowptr[n] = sh_carry;
}

__global__ __launch_bounds__(256)
void scatter_k(const void* __restrict__ ei, const int* __restrict__ flag,
               const int* __restrict__ rowptr, int* __restrict__ fill,
               int* __restrict__ csr_src) {
    int e = blockIdx.x * 256 + threadIdx.x;
    if (e >= ETOT) return;
    int is64 = *flag;
    int src, dst;
    if (e < NEDGES) {
        src = load_idx(ei, is64, (size_t)e);
        dst = load_idx(ei, is64, (size_t)NEDGES + e);
    } else {
        src = e - NEDGES; dst = src;
    }
    int pos = rowptr[dst] + atomicAdd(&fill[dst], 1);
    csr_src[pos] = src;
}

// ---------------------------------------------------------------------------
// fp32 tiled GEMM: C[M,N] = A[M,K] @ B[K,N]; 64x64 tile, BK=16, 256 threads
__global__ __launch_bounds__(256)
void gemm_k(const float* __restrict__ A, const float* __restrict__ B,
            float* __restrict__ C, int M, int N, int K) {
    __shared__ float As[16][64];  // [k][m]
    __shared__ float Bs[16][64];  // [k][n]
    const int tid = threadIdx.x;
    const int bm = blockIdx.y * 64;
    const int bn = blockIdx.x * 64;
    const int tr = tid >> 4;      // 0..15
    const int tc = tid & 15;      // 0..15
    const int arow = tid >> 2;           // 0..63
    const int akoff = (tid & 3) * 4;     // 0,4,8,12
    const int bkrow = tid >> 4;          // 0..15
    const int bcoff = (tid & 15) * 4;
    float acc[4][4] = {};
    for (int k0 = 0; k0 < K; k0 += 16) {
        float4 av = {0.f, 0.f, 0.f, 0.f};
        int row = bm + arow;
        if (row < M)
            av = *(const float4*)(A + (size_t)row * K + k0 + akoff);
        float4 bv = *(const float4*)(B + (size_t)(k0 + bkrow) * N + bn + bcoff);
        __syncthreads();
        As[akoff + 0][arow] = av.x;
        As[akoff + 1][arow] = av.y;
        As[akoff + 2][arow] = av.z;
        As[akoff + 3][arow] = av.w;
        *(float4*)&Bs[bkrow][bcoff] = bv;
        __syncthreads();
        #pragma unroll
        for (int k = 0; k < 16; ++k) {
            float a0 = As[k][tr * 4 + 0], a1 = As[k][tr * 4 + 1];
            float a2 = As[k][tr * 4 + 2], a3 = As[k][tr * 4 + 3];
            float b0 = Bs[k][tc * 4 + 0], b1 = Bs[k][tc * 4 + 1];
            float b2 = Bs[k][tc * 4 + 2], b3 = Bs[k][tc * 4 + 3];
            acc[0][0] += a0 * b0; acc[0][1] += a0 * b1; acc[0][2] += a0 * b2; acc[0][3] += a0 * b3;
            acc[1][0] += a1 * b0; acc[1][1] += a1 * b1; acc[1][2] += a1 * b2; acc[1][3] += a1 * b3;
            acc[2][0] += a2 * b0; acc[2][1] += a2 * b1; acc[2][2] += a2 * b2; acc[2][3] += a2 * b3;
            acc[3][0] += a3 * b0; acc[3][1] += a3 * b1; acc[3][2] += a3 * b2; acc[3][3] += a3 * b3;
        }
    }
    #pragma unroll
    for (int i = 0; i < 4; ++i) {
        int row = bm + tr * 4 + i;
        if (row < M) {
            float4 v = {acc[i][0], acc[i][1], acc[i][2], acc[i][3]};
            *(float4*)(C + (size_t)row * N + bn + tc * 4) = v;
        }
    }
}

// ---------------------------------------------------------------------------
// s[n,h] = sum_c h[n,h,c]*a_src[h,c]; d likewise. One wave per node.
template<int H>
__global__ __launch_bounds__(256)
void sd_k(const float* __restrict__ hfeat, const float* __restrict__ a_src,
          const float* __restrict__ a_dst, float* __restrict__ s,
          float* __restrict__ d, int n) {
    const int lane = threadIdx.x & 63;
    const int node = blockIdx.x * 4 + (threadIdx.x >> 6);
    if (node >= n) return;
    const float* row = hfeat + (size_t)node * (H * 64);
    #pragma unroll
    for (int h = 0; h < H; ++h) {
        float f = row[h * 64 + lane];
        float vs = f * a_src[h * 64 + lane];
        float vd = f * a_dst[h * 64 + lane];
        #pragma unroll
        for (int m = 32; m; m >>= 1) {
            vs += __shfl_xor(vs, m);
            vd += __shfl_xor(vd, m);
        }
        if (lane == 0) { s[node * H + h] = vs; d[node * H + h] = vd; }
    }
}

// ---------------------------------------------------------------------------
// GAT attention + aggregation, one wave per dst node. out = relu(agg + bias).
template<int H>
__global__ __launch_bounds__(256)
void agg_k(const float* __restrict__ hfeat, const float* __restrict__ s,
           const float* __restrict__ d, const float* __restrict__ bias,
           const int* __restrict__ rowptr, const int* __restrict__ csr_src,
           float* __restrict__ out, int n) {
    const int lane = threadIdx.x & 63;
    const int node = blockIdx.x * 4 + (threadIdx.x >> 6);
    if (node >= n) return;
    const int beg = rowptr[node];
    const int end = rowptr[node + 1];
    float dh[H], mx[H], dn[H], inv[H], acc[H];
    #pragma unroll
    for (int h = 0; h < H; ++h) {
        dh[h] = d[node * H + h];
        mx[h] = -3.0e38f; dn[h] = 0.f; acc[h] = 0.f;
    }
    // pass 1: per-head max of leaky_relu(s[src]+d[dst])
    for (int i = beg + lane; i < end; i += 64) {
        int sidx = csr_src[i];
        #pragma unroll
        for (int h = 0; h < H; ++h) {
            float e = s[sidx * H + h] + dh[h];
            e = (e > 0.f) ? e : 0.2f * e;
            mx[h] = fmaxf(mx[h], e);
        }
    }
    #pragma unroll
    for (int h = 0; h < H; ++h)
        #pragma unroll
        for (int m = 32; m; m >>= 1) mx[h] = fmaxf(mx[h], __shfl_xor(mx[h], m));
    // pass 2: denom
    for (int i = beg + lane; i < end; i += 64) {
        int sidx = csr_src[i];
        #pragma unroll
        for (int h = 0; h < H; ++h) {
            float e = s[sidx * H + h] + dh[h];
            e = (e > 0.f) ? e : 0.2f * e;
            dn[h] += __expf(e - mx[h]);
        }
    }
    #pragma unroll
    for (int h = 0; h < H; ++h) {
        #pragma unroll
        for (int m = 32; m; m >>= 1) dn[h] += __shfl_xor(dn[h], m);
        inv[h] = 1.f / (dn[h] + 1e-16f);
    }
    // pass 3: aggregate alpha * h[src]; lane owns channel c=lane
    for (int i = beg; i < end; ++i) {
        int sidx = csr_src[i];
        const float* hrow = hfeat + (size_t)sidx * (H * 64);
        #pragma unroll
        for (int h = 0; h < H; ++h) {
            float e = s[sidx * H + h] + dh[h];
            e = (e > 0.f) ? e : 0.2f * e;
            float a = __expf(e - mx[h]) * inv[h];
            acc[h] += a * hrow[h * 64 + lane];
        }
    }
    #pragma unroll
    for (int h = 0; h < H; ++h) {
        float v = acc[h] + bias[h * 64 + lane];
        out[(size_t)node * (H * 64) + h * 64 + lane] = fmaxf(v, 0.f);
    }
}

// ---------------------------------------------------------------------------
// Fused FF: out = softmax(relu(in@Wf1+bf1)@Wf2+bf2). Wave per node, weights in LDS.
__global__ __launch_bounds__(256)
void ff_k(const float* __restrict__ in, const float* __restrict__ Wf1,
          const float* __restrict__ bf1, const float* __restrict__ Wf2,
          const float* __restrict__ bf2, float* __restrict__ out, int n) {
    __shared__ float w1[64 * 64];
    __shared__ float w2[64 * 64];
    __shared__ float xrow[4][64];
    __shared__ float yrow[4][64];
    const int tid = threadIdx.x;
    for (int i = tid; i < 64 * 64; i += 256) { w1[i] = Wf1[i]; w2[i] = Wf2[i]; }
    const int wv = tid >> 6;
    const int lane = tid & 63;
    const int node = blockIdx.x * 4 + wv;
    const int nd = node < n ? node : (n - 1);
    float x = in[(size_t)nd * 64 + lane];
    xrow[wv][lane] = x;
    __syncthreads();
    float y = bf1[lane];
    #pragma unroll 8
    for (int k = 0; k < 64; ++k) y += xrow[wv][k] * w1[k * 64 + lane];
    y = fmaxf(y, 0.f);
    yrow[wv][lane] = y;
    __syncthreads();
    float z = bf2[lane];
    #pragma unroll 8
    for (int k = 0; k < 64; ++k) z += yrow[wv][k] * w2[k * 64 + lane];
    float m = z;
    #pragma unroll
    for (int dd = 32; dd; dd >>= 1) m = fmaxf(m, __shfl_xor(m, dd));
    float ex = __expf(z - m);
    float sum = ex;
    #pragma unroll
    for (int dd = 32; dd; dd >>= 1) sum += __shfl_xor(sum, dd);
    if (node < n) out[(size_t)node * 64 + lane] = ex / sum;
}

// ---------------------------------------------------------------------------
extern "C" void kernel_launch(void* const* d_in, const int* in_sizes, int n_in,
                              void* d_out, int out_size, void* d_ws, size_t ws_size,
                              hipStream_t stream) {
    const float* x      = (const float*)d_in[0];
    const void*  ei     = d_in[1];
    const float* W1     = (const float*)d_in[2];
    const float* a_src1 = (const float*)d_in[3];
    const float* a_dst1 = (const float*)d_in[4];
    const float* b1     = (const float*)d_in[5];
    const float* W2     = (const float*)d_in[6];
    const float* a_src2 = (const float*)d_in[7];
    const float* a_dst2 = (const float*)d_in[8];
    const float* b2     = (const float*)d_in[9];
    const float* Wf1    = (const float*)d_in[10];
    const float* bf1    = (const float*)d_in[11];
    const float* Wf2    = (const float*)d_in[12];
    const float* bf2    = (const float*)d_in[13];
    float* outp = (float*)d_out;

    // workspace carve-up (256B aligned)
    char* ws = (char*)d_ws;
    size_t off = 0;
    auto take = [&](size_t bytes) -> char* {
        char* p = ws + off;
        off += (bytes + 255) & ~(size_t)255;
        return p;
    };
    int*   flag   = (int*)take(4);
    int*   count  = (int*)take((size_t)NNODES * 4);
    int*   fill   = (int*)take((size_t)NNODES * 4);
    int*   rowptr = (int*)take((size_t)(NNODES + 1) * 4);
    int*   csr    = (int*)take((size_t)ETOT * 4);
    float* h1     = (float*)take((size_t)NNODES * 256 * 4);
    float* agg1   = (float*)take((size_t)NNODES * 256 * 4);
    float* s1     = (float*)take((size_t)NNODES * HEADS * 4);
    float* d1     = (float*)take((size_t)NNODES * HEADS * 4);
    // reuse dead buffers for layer 2
    float* h2   = h1;    // h1 dead after agg1
    float* s2   = s1;
    float* d2   = d1;
    float* agg2 = agg1;  // agg1 dead after gemm2

    // CSR build (shared by both GAT layers)
    detect_k<<<1, 1, 0, stream>>>((const unsigned*)ei, flag);
    hipMemsetAsync(count, 0, (size_t)NNODES * 4, stream);
    hipMemsetAsync(fill, 0, (size_t)NNODES * 4, stream);
    const int eblocks = (ETOT + 255) / 256;
    hist_k<<<eblocks, 256, 0, stream>>>(ei, flag, count);
    scan_k<<<1, 1024, 0, stream>>>(count, rowptr, NNODES);
    scatter_k<<<eblocks, 256, 0, stream>>>(ei, flag, rowptr, fill, csr);

    const int nodeblocks = NNODES / 4;  // 12500, exact
    const dim3 g1((256 + 63) / 64, (NNODES + 63) / 64);
    const dim3 g2((64 + 63) / 64, (NNODES + 63) / 64);

    // Layer 1: h1 = x@W1; s,d; attention+aggregate (+b1, relu)
    gemm_k<<<g1, 256, 0, stream>>>(x, W1, h1, NNODES, 256, 256);
    sd_k<HEADS><<<nodeblocks, 256, 0, stream>>>(h1, a_src1, a_dst1, s1, d1, NNODES);
    agg_k<HEADS><<<nodeblocks, 256, 0, stream>>>(h1, s1, d1, b1, rowptr, csr, agg1, NNODES);

    // Layer 2: h2 = agg1@W2; s,d; attention+aggregate (+b2, relu)
    gemm_k<<<g2, 256, 0, stream>>>(agg1, W2, h2, NNODES, 64, 256);
    sd_k<1><<<nodeblocks, 256, 0, stream>>>(h2, a_src2, a_dst2, s2, d2, NNODES);
    agg_k<1><<<nodeblocks, 256, 0, stream>>>(h2, s2, d2, b2, rowptr, csr, agg2, NNODES);

    // FF + softmax
    ff_k<<<nodeblocks, 256, 0, stream>>>(agg2, Wf1, bf1, Wf2, bf2, outp, NNODES);
}

// Round 2
// 550.496 us; speedup vs baseline: 1.0908x; 1.0908x over previous
//
#include <hip/hip_runtime.h>

// Problem constants (from reference)
#define NNODES 50000
#define NEDGES 800000
#define INDIM  256
#define HIDC   64
#define HEADS  4
static constexpr int ETOT = NEDGES + NNODES;  // edges + self loops

// ---------------------------------------------------------------------------
// edge_index element-width detection: reference declares int64 but harness may
// hand us int32. If int64 (values < 2^31), every odd 32-bit word is zero.
__global__ void detect_k(const unsigned* __restrict__ ei32, int* __restrict__ flag) {
    int is64 = 1;
    for (int i = 1; i < 256; i += 2)
        if (ei32[i] != 0u) { is64 = 0; break; }
    *flag = is64;
}

__device__ __forceinline__ int load_idx(const void* ei, int is64, size_t pos) {
    return is64 ? (int)((const long long*)ei)[pos] : ((const int*)ei)[pos];
}

// ---------------------------------------------------------------------------
// CSR build: histogram of dst, exclusive scan, scatter src ids
__global__ __launch_bounds__(256)
void hist_k(const void* __restrict__ ei, const int* __restrict__ flag,
            int* __restrict__ count) {
    int e = blockIdx.x * 256 + threadIdx.x;
    if (e >= ETOT) return;
    int is64 = *flag;
    int dst = (e < NEDGES) ? load_idx(ei, is64, (size_t)NEDGES + e) : (e - NEDGES);
    atomicAdd(&count[dst], 1);
}

__global__ __launch_bounds__(1024)
void scan_k(const int* __restrict__ count, int* __restrict__ rowptr, int n) {
    __shared__ int wsum[16];
    __shared__ int sh_carry;
    const int tid = threadIdx.x;
    const int lane = tid & 63;
    const int w = tid >> 6;
    if (tid == 0) sh_carry = 0;
    __syncthreads();
    for (int base = 0; base < n; base += 1024) {
        int i = base + tid;
        int v = (i < n) ? count[i] : 0;
        int x = v;
        #pragma unroll
        for (int dd = 1; dd < 64; dd <<= 1) {
            int y = __shfl_up(x, dd);
            if (lane >= dd) x += y;
        }
        if (lane == 63) wsum[w] = x;
        __syncthreads();
        int woff = 0, total = 0;
        #pragma unroll
        for (int j = 0; j < 16; ++j) {
            if (j < w) woff += wsum[j];
            total += wsum[j];
        }
        if (i < n) rowptr[i] = sh_carry + woff + x - v;
        __syncthreads();
        if (tid == 0) sh_carry += total;
        __syncthreads();
    }
    if (tid == 0) rowptr[n] = sh_carry;
}

__global__ __launch_bounds__(256)
void scatter_k(const void* __restrict__ ei, const int* __restrict__ flag,
               const int* __restrict__ rowptr, int* __restrict__ fill,
               int* __restrict__ csr_src) {
    int e = blockIdx.x * 256 + threadIdx.x;
    if (e >= ETOT) return;
    int is64 = *flag;
    int src, dst;
    if (e < NEDGES) {
        src = load_idx(ei, is64, (size_t)e);
        dst = load_idx(ei, is64, (size_t)NEDGES + e);
    } else {
        src = e - NEDGES; dst = src;
    }
    int pos = rowptr[dst] + atomicAdd(&fill[dst], 1);
    csr_src[pos] = src;
}

// ---------------------------------------------------------------------------
// fp32 tiled GEMM: C[M,N] = A[M,K]@B[K,N]; BM=128, BN in {128,64}, BK=16,
// 256 threads, micro 8x(BN/16) => 64 (or 32) FMA per thread-k vs 3-4 ds_read_b128
__global__ __launch_bounds__(256)
void gemm128_k(const float* __restrict__ A, const float* __restrict__ B,
               float* __restrict__ C, int M, int N, int K) {
    __shared__ float As[16][128];
    __shared__ float Bs[16][128];
    const int tid = threadIdx.x;
    const int bm = blockIdx.y * 128;
    const int bn = blockIdx.x * 128;
    const int tr = tid >> 4;
    const int tc = tid & 15;
    const int arow = tid >> 1;
    const int acol = (tid & 1) * 8;
    int aload_row = bm + arow; if (aload_row >= M) aload_row = M - 1;
    const float* Aptr = A + (size_t)aload_row * K + acol;
    const int bk = tid >> 5;           // 0..7
    const int bc = (tid & 31) * 4;
    float acc[8][8] = {};
    for (int k0 = 0; k0 < K; k0 += 16) {
        float4 a0 = *(const float4*)(Aptr + k0);
        float4 a1 = *(const float4*)(Aptr + k0 + 4);
        float4 bv0 = *(const float4*)(B + (size_t)(k0 + bk) * N + bn + bc);
        float4 bv1 = *(const float4*)(B + (size_t)(k0 + bk + 8) * N + bn + bc);
        __syncthreads();
        As[acol + 0][arow] = a0.x; As[acol + 1][arow] = a0.y;
        As[acol + 2][arow] = a0.z; As[acol + 3][arow] = a0.w;
        As[acol + 4][arow] = a1.x; As[acol + 5][arow] = a1.y;
        As[acol + 6][arow] = a1.z; As[acol + 7][arow] = a1.w;
        *(float4*)&Bs[bk][bc] = bv0;
        *(float4*)&Bs[bk + 8][bc] = bv1;
        __syncthreads();
        #pragma unroll
        for (int k = 0; k < 16; ++k) {
            float a[8], b[8];
            #pragma unroll
            for (int i = 0; i < 8; ++i) a[i] = As[k][tr * 8 + i];
            #pragma unroll
            for (int j = 0; j < 8; ++j) b[j] = Bs[k][tc * 8 + j];
            #pragma unroll
            for (int i = 0; i < 8; ++i)
                #pragma unroll
                for (int j = 0; j < 8; ++j)
                    acc[i][j] += a[i] * b[j];
        }
    }
    #pragma unroll
    for (int i = 0; i < 8; ++i) {
        int row = bm + tr * 8 + i;
        if (row < M) {
            #pragma unroll
            for (int j0 = 0; j0 < 8; j0 += 4) {
                float4 v = {acc[i][j0], acc[i][j0 + 1], acc[i][j0 + 2], acc[i][j0 + 3]};
                *(float4*)(C + (size_t)row * N + bn + tc * 8 + j0) = v;
            }
        }
    }
}

__global__ __launch_bounds__(256)
void gemm64_k(const float* __restrict__ A, const float* __restrict__ B,
              float* __restrict__ C, int M, int N, int K) {
    __shared__ float As[16][128];
    __shared__ float Bs[16][64];
    const int tid = threadIdx.x;
    const int bm = blockIdx.y * 128;
    const int bn = blockIdx.x * 64;
    const int tr = tid >> 4;
    const int tc = tid & 15;
    const int arow = tid >> 1;
    const int acol = (tid & 1) * 8;
    int aload_row = bm + arow; if (aload_row >= M) aload_row = M - 1;
    const float* Aptr = A + (size_t)aload_row * K + acol;
    const int bk = tid >> 4;           // 0..15
    const int bc = (tid & 15) * 4;
    float acc[8][4] = {};
    for (int k0 = 0; k0 < K; k0 += 16) {
        float4 a0 = *(const float4*)(Aptr + k0);
        float4 a1 = *(const float4*)(Aptr + k0 + 4);
        float4 bv0 = *(const float4*)(B + (size_t)(k0 + bk) * N + bn + bc);
        __syncthreads();
        As[acol + 0][arow] = a0.x; As[acol + 1][arow] = a0.y;
        As[acol + 2][arow] = a0.z; As[acol + 3][arow] = a0.w;
        As[acol + 4][arow] = a1.x; As[acol + 5][arow] = a1.y;
        As[acol + 6][arow] = a1.z; As[acol + 7][arow] = a1.w;
        *(float4*)&Bs[bk][bc] = bv0;
        __syncthreads();
        #pragma unroll
        for (int k = 0; k < 16; ++k) {
            float a[8], b[4];
            #pragma unroll
            for (int i = 0; i < 8; ++i) a[i] = As[k][tr * 8 + i];
            #pragma unroll
            for (int j = 0; j < 4; ++j) b[j] = Bs[k][tc * 4 + j];
            #pragma unroll
            for (int i = 0; i < 8; ++i)
                #pragma unroll
                for (int j = 0; j < 4; ++j)
                    acc[i][j] += a[i] * b[j];
        }
    }
    #pragma unroll
    for (int i = 0; i < 8; ++i) {
        int row = bm + tr * 8 + i;
        if (row < M) {
            float4 v = {acc[i][0], acc[i][1], acc[i][2], acc[i][3]};
            *(float4*)(C + (size_t)row * N + bn + tc * 4) = v;
        }
    }
}

// ---------------------------------------------------------------------------
// s[n,h] = sum_c h[n,h,c]*a_src[h,c]; d likewise. One wave per node.
template<int H>
__global__ __launch_bounds__(256)
void sd_k(const float* __restrict__ hfeat, const float* __restrict__ a_src,
          const float* __restrict__ a_dst, float* __restrict__ s,
          float* __restrict__ d, int n) {
    const int lane = threadIdx.x & 63;
    const int node = blockIdx.x * 4 + (threadIdx.x >> 6);
    if (node >= n) return;
    const float* row = hfeat + (size_t)node * (H * 64);
    #pragma unroll
    for (int h = 0; h < H; ++h) {
        float f = row[h * 64 + lane];
        float vs = f * a_src[h * 64 + lane];
        float vd = f * a_dst[h * 64 + lane];
        #pragma unroll
        for (int m = 32; m; m >>= 1) {
            vs += __shfl_xor(vs, m);
            vd += __shfl_xor(vd, m);
        }
        if (lane == 0) { s[node * H + h] = vs; d[node * H + h] = vd; }
    }
}

// ---------------------------------------------------------------------------
__device__ __forceinline__ float leaky(float e) { return (e > 0.f) ? e : 0.2f * e; }

__device__ __forceinline__ float sel4(const float v[4], int idx) {
    float r = v[0];
    r = (idx == 1) ? v[1] : r;
    r = (idx == 2) ? v[2] : r;
    r = (idx == 3) ? v[3] : r;
    return r;
}

// GAT attention + aggregation, one wave per dst node. out = relu(agg + bias).
// EB: ebuf[E*H] holds e (pass1) then ex (pass2); pass3 reads alpha coalesced.
template<int H, bool EB>
__global__ __launch_bounds__(256)
void agg_k(const float* __restrict__ hfeat, const float* __restrict__ s,
           const float* __restrict__ d, const float* __restrict__ bias,
           const int* __restrict__ rowptr, const int* __restrict__ csr_src,
           float* __restrict__ ebuf, float* __restrict__ out, int n) {
    const int lane = threadIdx.x & 63;
    const int node = blockIdx.x * 4 + (threadIdx.x >> 6);
    if (node >= n) return;
    const int beg = rowptr[node];
    const int end = rowptr[node + 1];
    float dh[H], mx[H], dn[H], inv[H];
    #pragma unroll
    for (int h = 0; h < H; ++h) {
        dh[h] = d[node * H + h];
        mx[h] = -3.0e38f; dn[h] = 0.f;
    }
    // pass 1: e = leaky(s[src]+d[dst]); track max; optionally store e
    for (int i = beg + lane; i < end; i += 64) {
        int sidx = csr_src[i];
        if constexpr (H == 4) {
            float4 sv = *(const float4*)(s + (size_t)sidx * 4);
            float4 e;
            e.x = leaky(sv.x + dh[0]); e.y = leaky(sv.y + dh[1]);
            e.z = leaky(sv.z + dh[2]); e.w = leaky(sv.w + dh[3]);
            if (EB) *(float4*)(ebuf + (size_t)i * 4) = e;
            mx[0] = fmaxf(mx[0], e.x); mx[1] = fmaxf(mx[1], e.y);
            mx[2] = fmaxf(mx[2], e.z); mx[3] = fmaxf(mx[3], e.w);
        } else {
            float e = leaky(s[sidx] + dh[0]);
            if (EB) ebuf[i] = e;
            mx[0] = fmaxf(mx[0], e);
        }
    }
    #pragma unroll
    for (int h = 0; h < H; ++h)
        #pragma unroll
        for (int m = 32; m; m >>= 1) mx[h] = fmaxf(mx[h], __shfl_xor(mx[h], m));
    // pass 2: ex = exp(e-mx); denom; optionally store ex
    for (int i = beg + lane; i < end; i += 64) {
        if constexpr (H == 4) {
            float4 e;
            if (EB) e = *(const float4*)(ebuf + (size_t)i * 4);
            else {
                int sidx = csr_src[i];
                float4 sv = *(const float4*)(s + (size_t)sidx * 4);
                e.x = leaky(sv.x + dh[0]); e.y = leaky(sv.y + dh[1]);
                e.z = leaky(sv.z + dh[2]); e.w = leaky(sv.w + dh[3]);
            }
            float4 ex;
            ex.x = __expf(e.x - mx[0]); ex.y = __expf(e.y - mx[1]);
            ex.z = __expf(e.z - mx[2]); ex.w = __expf(e.w - mx[3]);
            if (EB) *(float4*)(ebuf + (size_t)i * 4) = ex;
            dn[0] += ex.x; dn[1] += ex.y; dn[2] += ex.z; dn[3] += ex.w;
        } else {
            float e;
            if (EB) e = ebuf[i];
            else { int sidx = csr_src[i]; e = leaky(s[sidx] + dh[0]); }
            float ex = __expf(e - mx[0]);
            if (EB) ebuf[i] = ex;
            dn[0] += ex;
        }
    }
    #pragma unroll
    for (int h = 0; h < H; ++h) {
        #pragma unroll
        for (int m = 32; m; m >>= 1) dn[h] += __shfl_xor(dn[h], m);
        inv[h] = 1.f / (dn[h] + 1e-16f);
    }
    // pass 3: aggregate alpha * h[src]
    if constexpr (H == 4) {
        // lane l holds channels 4l..4l+3  => head = l>>4, one float4 load/edge
        const int head = lane >> 4;
        const float invh = sel4(inv, head);
        const float mxh = sel4(mx, head);
        const float dhh = sel4(dh, head);
        const float4* H4 = (const float4*)hfeat;
        float4 acc = {0.f, 0.f, 0.f, 0.f};
        int i = beg;
        for (; i + 1 < end; i += 2) {
            int s0 = csr_src[i], s1 = csr_src[i + 1];
            float al0, al1;
            if (EB) {
                al0 = ebuf[(size_t)i * 4 + head] * invh;
                al1 = ebuf[(size_t)(i + 1) * 4 + head] * invh;
            } else {
                al0 = __expf(leaky(s[(size_t)s0 * 4 + head] + dhh) - mxh) * invh;
                al1 = __expf(leaky(s[(size_t)s1 * 4 + head] + dhh) - mxh) * invh;
            }
            float4 h0 = H4[(size_t)s0 * 64 + lane];
            float4 h1 = H4[(size_t)s1 * 64 + lane];
            acc.x += al0 * h0.x + al1 * h1.x;
            acc.y += al0 * h0.y + al1 * h1.y;
            acc.z += al0 * h0.z + al1 * h1.z;
            acc.w += al0 * h0.w + al1 * h1.w;
        }
        if (i < end) {
            int s0 = csr_src[i];
            float al0;
            if (EB) al0 = ebuf[(size_t)i * 4 + head] * invh;
            else    al0 = __expf(leaky(s[(size_t)s0 * 4 + head] + dhh) - mxh) * invh;
            float4 h0 = H4[(size_t)s0 * 64 + lane];
            acc.x += al0 * h0.x; acc.y += al0 * h0.y;
            acc.z += al0 * h0.z; acc.w += al0 * h0.w;
        }
        float4 bv = ((const float4*)bias)[lane];
        float4 o;
        o.x = fmaxf(acc.x + bv.x, 0.f); o.y = fmaxf(acc.y + bv.y, 0.f);
        o.z = fmaxf(acc.z + bv.z, 0.f); o.w = fmaxf(acc.w + bv.w, 0.f);
        ((float4*)out)[(size_t)node * 64 + lane] = o;
    } else {
        const float invh = inv[0];
        float acc = 0.f;
        int i = beg;
        for (; i + 3 < end; i += 4) {
            int s0 = csr_src[i], s1 = csr_src[i + 1], s2 = csr_src[i + 2], s3 = csr_src[i + 3];
            float a0, a1, a2, a3;
            if (EB) {
                a0 = ebuf[i] * invh; a1 = ebuf[i + 1] * invh;
                a2 = ebuf[i + 2] * invh; a3 = ebuf[i + 3] * invh;
            } else {
                a0 = __expf(leaky(s[s0] + dh[0]) - mx[0]) * invh;
                a1 = __expf(leaky(s[s1] + dh[0]) - mx[0]) * invh;
                a2 = __expf(leaky(s[s2] + dh[0]) - mx[0]) * invh;
                a3 = __expf(leaky(s[s3] + dh[0]) - mx[0]) * invh;
            }
            acc += a0 * hfeat[(size_t)s0 * 64 + lane];
            acc += a1 * hfeat[(size_t)s1 * 64 + lane];
            acc += a2 * hfeat[(size_t)s2 * 64 + lane];
            acc += a3 * hfeat[(size_t)s3 * 64 + lane];
        }
        for (; i < end; ++i) {
            int s0 = csr_src[i];
            float a0;
            if (EB) a0 = ebuf[i] * invh;
            else    a0 = __expf(leaky(s[s0] + dh[0]) - mx[0]) * invh;
            acc += a0 * hfeat[(size_t)s0 * 64 + lane];
        }
        float v = acc + bias[lane];
        out[(size_t)node * 64 + lane] = fmaxf(v, 0.f);
    }
}

// ---------------------------------------------------------------------------
// Fused FF: out = softmax(relu(in@Wf1+bf1)@Wf2+bf2). Wave per node, weights in LDS.
__global__ __launch_bounds__(256)
void ff_k(const float* __restrict__ in, const float* __restrict__ Wf1,
          const float* __restrict__ bf1, const float* __restrict__ Wf2,
          const float* __restrict__ bf2, float* __restrict__ out, int n) {
    __shared__ float w1[64 * 64];
    __shared__ float w2[64 * 64];
    __shared__ float xrow[4][64];
    __shared__ float yrow[4][64];
    const int tid = threadIdx.x;
    for (int i = tid; i < 64 * 64; i += 256) { w1[i] = Wf1[i]; w2[i] = Wf2[i]; }
    const int wv = tid >> 6;
    const int lane = tid & 63;
    const int node = blockIdx.x * 4 + wv;
    const int nd = node < n ? node : (n - 1);
    float x = in[(size_t)nd * 64 + lane];
    xrow[wv][lane] = x;
    __syncthreads();
    float y = bf1[lane];
    #pragma unroll 8
    for (int k = 0; k < 64; ++k) y += xrow[wv][k] * w1[k * 64 + lane];
    y = fmaxf(y, 0.f);
    yrow[wv][lane] = y;
    __syncthreads();
    float z = bf2[lane];
    #pragma unroll 8
    for (int k = 0; k < 64; ++k) z += yrow[wv][k] * w2[k * 64 + lane];
    float m = z;
    #pragma unroll
    for (int dd = 32; dd; dd >>= 1) m = fmaxf(m, __shfl_xor(m, dd));
    float ex = __expf(z - m);
    float sum = ex;
    #pragma unroll
    for (int dd = 32; dd; dd >>= 1) sum += __shfl_xor(sum, dd);
    if (node < n) out[(size_t)node * 64 + lane] = ex / sum;
}

// ---------------------------------------------------------------------------
extern "C" void kernel_launch(void* const* d_in, const int* in_sizes, int n_in,
                              void* d_out, int out_size, void* d_ws, size_t ws_size,
                              hipStream_t stream) {
    const float* x      = (const float*)d_in[0];
    const void*  ei     = d_in[1];
    const float* W1     = (const float*)d_in[2];
    const float* a_src1 = (const float*)d_in[3];
    const float* a_dst1 = (const float*)d_in[4];
    const float* b1     = (const float*)d_in[5];
    const float* W2     = (const float*)d_in[6];
    const float* a_src2 = (const float*)d_in[7];
    const float* a_dst2 = (const float*)d_in[8];
    const float* b2     = (const float*)d_in[9];
    const float* Wf1    = (const float*)d_in[10];
    const float* bf1    = (const float*)d_in[11];
    const float* Wf2    = (const float*)d_in[12];
    const float* bf2    = (const float*)d_in[13];
    float* outp = (float*)d_out;

    // workspace carve-up (256B aligned)
    char* ws = (char*)d_ws;
    size_t off = 0;
    auto take = [&](size_t bytes) -> char* {
        char* p = ws + off;
        off += (bytes + 255) & ~(size_t)255;
        return p;
    };
    int*   flag   = (int*)take(4);
    int*   count  = (int*)take((size_t)NNODES * 4);
    int*   fill   = (int*)take((size_t)NNODES * 4);
    int*   rowptr = (int*)take((size_t)(NNODES + 1) * 4);
    int*   csr    = (int*)take((size_t)ETOT * 4);
    float* h1     = (float*)take((size_t)NNODES * 256 * 4);
    float* agg1   = (float*)take((size_t)NNODES * 256 * 4);
    float* s1     = (float*)take((size_t)NNODES * HEADS * 4);
    float* d1     = (float*)take((size_t)NNODES * HEADS * 4);
    float* ebuf   = (float*)take((size_t)ETOT * HEADS * 4);
    const bool eb_ok = (off <= ws_size);
    // reuse dead buffers for layer 2
    float* h2   = h1;    // h1 dead after agg1
    float* s2   = s1;
    float* d2   = d1;
    float* agg2 = agg1;  // agg1 dead after gemm2

    // CSR build (shared by both GAT layers)
    detect_k<<<1, 1, 0, stream>>>((const unsigned*)ei, flag);
    hipMemsetAsync(count, 0, (size_t)NNODES * 4, stream);
    hipMemsetAsync(fill, 0, (size_t)NNODES * 4, stream);
    const int eblocks = (ETOT + 255) / 256;
    hist_k<<<eblocks, 256, 0, stream>>>(ei, flag, count);
    scan_k<<<1, 1024, 0, stream>>>(count, rowptr, NNODES);
    scatter_k<<<eblocks, 256, 0, stream>>>(ei, flag, rowptr, fill, csr);

    const int nodeblocks = NNODES / 4;  // 12500, exact
    const dim3 gg1(256 / 128, (NNODES + 127) / 128);
    const dim3 gg2(64 / 64, (NNODES + 127) / 128);

    // Layer 1: h1 = x@W1; s,d; attention+aggregate (+b1, relu)
    gemm128_k<<<gg1, 256, 0, stream>>>(x, W1, h1, NNODES, 256, 256);
    sd_k<HEADS><<<nodeblocks, 256, 0, stream>>>(h1, a_src1, a_dst1, s1, d1, NNODES);
    if (eb_ok)
        agg_k<HEADS, true><<<nodeblocks, 256, 0, stream>>>(h1, s1, d1, b1, rowptr, csr, ebuf, agg1, NNODES);
    else
        agg_k<HEADS, false><<<nodeblocks, 256, 0, stream>>>(h1, s1, d1, b1, rowptr, csr, ebuf, agg1, NNODES);

    // Layer 2: h2 = agg1@W2; s,d; attention+aggregate (+b2, relu)
    gemm64_k<<<gg2, 256, 0, stream>>>(agg1, W2, h2, NNODES, 64, 256);
    sd_k<1><<<nodeblocks, 256, 0, stream>>>(h2, a_src2, a_dst2, s2, d2, NNODES);
    if (eb_ok)
        agg_k<1, true><<<nodeblocks, 256, 0, stream>>>(h2, s2, d2, b2, rowptr, csr, ebuf, agg2, NNODES);
    else
        agg_k<1, false><<<nodeblocks, 256, 0, stream>>>(h2, s2, d2, b2, rowptr, csr, ebuf, agg2, NNODES);

    // FF + softmax
    ff_k<<<nodeblocks, 256, 0, stream>>>(agg2, Wf1, bf1, Wf2, bf2, outp, NNODES);
}

// Round 3
// 496.395 us; speedup vs baseline: 1.2097x; 1.1090x over previous
//
#include <hip/hip_runtime.h>

// Problem constants (from reference)
#define NNODES 50000
#define NEDGES 800000
#define INDIM  256
#define HIDC   64
#define HEADS  4
static constexpr int ETOT = NEDGES + NNODES;  // edges + self loops

typedef _Float16 half4 __attribute__((ext_vector_type(4)));

// ---------------------------------------------------------------------------
// edge_index element-width detection: reference declares int64 but harness may
// hand us int32. If int64 (values < 2^31), every odd 32-bit word is zero.
__global__ void detect_k(const unsigned* __restrict__ ei32, int* __restrict__ flag) {
    int is64 = 1;
    for (int i = 1; i < 256; i += 2)
        if (ei32[i] != 0u) { is64 = 0; break; }
    *flag = is64;
}

__device__ __forceinline__ int load_idx(const void* ei, int is64, size_t pos) {
    return is64 ? (int)((const long long*)ei)[pos] : ((const int*)ei)[pos];
}

// ---------------------------------------------------------------------------
// CSR build: histogram of dst, exclusive scan, scatter src ids
__global__ __launch_bounds__(256)
void hist_k(const void* __restrict__ ei, const int* __restrict__ flag,
            int* __restrict__ count) {
    int e = blockIdx.x * 256 + threadIdx.x;
    if (e >= ETOT) return;
    int is64 = *flag;
    int dst = (e < NEDGES) ? load_idx(ei, is64, (size_t)NEDGES + e) : (e - NEDGES);
    atomicAdd(&count[dst], 1);
}

__global__ __launch_bounds__(1024)
void scan_k(const int* __restrict__ count, int* __restrict__ rowptr, int n) {
    __shared__ int wsum[16];
    __shared__ int sh_carry;
    const int tid = threadIdx.x;
    const int lane = tid & 63;
    const int w = tid >> 6;
    if (tid == 0) sh_carry = 0;
    __syncthreads();
    for (int base = 0; base < n; base += 1024) {
        int i = base + tid;
        int v = (i < n) ? count[i] : 0;
        int x = v;
        #pragma unroll
        for (int dd = 1; dd < 64; dd <<= 1) {
            int y = __shfl_up(x, dd);
            if (lane >= dd) x += y;
        }
        if (lane == 63) wsum[w] = x;
        __syncthreads();
        int woff = 0, total = 0;
        #pragma unroll
        for (int j = 0; j < 16; ++j) {
            if (j < w) woff += wsum[j];
            total += wsum[j];
        }
        if (i < n) rowptr[i] = sh_carry + woff + x - v;
        __syncthreads();
        if (tid == 0) sh_carry += total;
        __syncthreads();
    }
    if (tid == 0) rowptr[n] = sh_carry;
}

__global__ __launch_bounds__(256)
void scatter_k(const void* __restrict__ ei, const int* __restrict__ flag,
               const int* __restrict__ rowptr, int* __restrict__ fill,
               int* __restrict__ csr_src) {
    int e = blockIdx.x * 256 + threadIdx.x;
    if (e >= ETOT) return;
    int is64 = *flag;
    int src, dst;
    if (e < NEDGES) {
        src = load_idx(ei, is64, (size_t)e);
        dst = load_idx(ei, is64, (size_t)NEDGES + e);
    } else {
        src = e - NEDGES; dst = src;
    }
    int pos = rowptr[dst] + atomicAdd(&fill[dst], 1);
    csr_src[pos] = src;
}

// ---------------------------------------------------------------------------
// fp32 tiled GEMM: C[M,N] = A[M,K]@B[K,N]; BM=128, BN in {128,64}, BK=16,
// 256 threads. Ch (optional) receives fp16 copy of C for the gather pass.
__global__ __launch_bounds__(256)
void gemm128_k(const float* __restrict__ A, const float* __restrict__ B,
               float* __restrict__ C, _Float16* __restrict__ Ch,
               int M, int N, int K) {
    __shared__ float As[16][128];
    __shared__ float Bs[16][128];
    const int tid = threadIdx.x;
    const int bm = blockIdx.y * 128;
    const int bn = blockIdx.x * 128;
    const int tr = tid >> 4;
    const int tc = tid & 15;
    const int arow = tid >> 1;
    const int acol = (tid & 1) * 8;
    int aload_row = bm + arow; if (aload_row >= M) aload_row = M - 1;
    const float* Aptr = A + (size_t)aload_row * K + acol;
    const int bk = tid >> 5;           // 0..7
    const int bc = (tid & 31) * 4;
    float acc[8][8] = {};
    for (int k0 = 0; k0 < K; k0 += 16) {
        float4 a0 = *(const float4*)(Aptr + k0);
        float4 a1 = *(const float4*)(Aptr + k0 + 4);
        float4 bv0 = *(const float4*)(B + (size_t)(k0 + bk) * N + bn + bc);
        float4 bv1 = *(const float4*)(B + (size_t)(k0 + bk + 8) * N + bn + bc);
        __syncthreads();
        As[acol + 0][arow] = a0.x; As[acol + 1][arow] = a0.y;
        As[acol + 2][arow] = a0.z; As[acol + 3][arow] = a0.w;
        As[acol + 4][arow] = a1.x; As[acol + 5][arow] = a1.y;
        As[acol + 6][arow] = a1.z; As[acol + 7][arow] = a1.w;
        *(float4*)&Bs[bk][bc] = bv0;
        *(float4*)&Bs[bk + 8][bc] = bv1;
        __syncthreads();
        #pragma unroll
        for (int k = 0; k < 16; ++k) {
            float a[8], b[8];
            #pragma unroll
            for (int i = 0; i < 8; ++i) a[i] = As[k][tr * 8 + i];
            #pragma unroll
            for (int j = 0; j < 8; ++j) b[j] = Bs[k][tc * 8 + j];
            #pragma unroll
            for (int i = 0; i < 8; ++i)
                #pragma unroll
                for (int j = 0; j < 8; ++j)
                    acc[i][j] += a[i] * b[j];
        }
    }
    #pragma unroll
    for (int i = 0; i < 8; ++i) {
        int row = bm + tr * 8 + i;
        if (row < M) {
            #pragma unroll
            for (int j0 = 0; j0 < 8; j0 += 4) {
                float4 v = {acc[i][j0], acc[i][j0 + 1], acc[i][j0 + 2], acc[i][j0 + 3]};
                *(float4*)(C + (size_t)row * N + bn + tc * 8 + j0) = v;
                if (Ch) {
                    half4 hv = {(_Float16)v.x, (_Float16)v.y, (_Float16)v.z, (_Float16)v.w};
                    *(half4*)(Ch + (size_t)row * N + bn + tc * 8 + j0) = hv;
                }
            }
        }
    }
}

__global__ __launch_bounds__(256)
void gemm64_k(const float* __restrict__ A, const float* __restrict__ B,
              float* __restrict__ C, _Float16* __restrict__ Ch,
              int M, int N, int K) {
    __shared__ float As[16][128];
    __shared__ float Bs[16][64];
    const int tid = threadIdx.x;
    const int bm = blockIdx.y * 128;
    const int bn = blockIdx.x * 64;
    const int tr = tid >> 4;
    const int tc = tid & 15;
    const int arow = tid >> 1;
    const int acol = (tid & 1) * 8;
    int aload_row = bm + arow; if (aload_row >= M) aload_row = M - 1;
    const float* Aptr = A + (size_t)aload_row * K + acol;
    const int bk = tid >> 4;           // 0..15
    const int bc = (tid & 15) * 4;
    float acc[8][4] = {};
    for (int k0 = 0; k0 < K; k0 += 16) {
        float4 a0 = *(const float4*)(Aptr + k0);
        float4 a1 = *(const float4*)(Aptr + k0 + 4);
        float4 bv0 = *(const float4*)(B + (size_t)(k0 + bk) * N + bn + bc);
        __syncthreads();
        As[acol + 0][arow] = a0.x; As[acol + 1][arow] = a0.y;
        As[acol + 2][arow] = a0.z; As[acol + 3][arow] = a0.w;
        As[acol + 4][arow] = a1.x; As[acol + 5][arow] = a1.y;
        As[acol + 6][arow] = a1.z; As[acol + 7][arow] = a1.w;
        *(float4*)&Bs[bk][bc] = bv0;
        __syncthreads();
        #pragma unroll
        for (int k = 0; k < 16; ++k) {
            float a[8], b[4];
            #pragma unroll
            for (int i = 0; i < 8; ++i) a[i] = As[k][tr * 8 + i];
            #pragma unroll
            for (int j = 0; j < 4; ++j) b[j] = Bs[k][tc * 4 + j];
            #pragma unroll
            for (int i = 0; i < 8; ++i)
                #pragma unroll
                for (int j = 0; j < 4; ++j)
                    acc[i][j] += a[i] * b[j];
        }
    }
    #pragma unroll
    for (int i = 0; i < 8; ++i) {
        int row = bm + tr * 8 + i;
        if (row < M) {
            float4 v = {acc[i][0], acc[i][1], acc[i][2], acc[i][3]};
            *(float4*)(C + (size_t)row * N + bn + tc * 4) = v;
            if (Ch) {
                half4 hv = {(_Float16)v.x, (_Float16)v.y, (_Float16)v.z, (_Float16)v.w};
                *(half4*)(Ch + (size_t)row * N + bn + tc * 4) = hv;
            }
        }
    }
}

// ---------------------------------------------------------------------------
// s[n,h] = sum_c h[n,h,c]*a_src[h,c]; d likewise. One wave per node.
template<int H>
__global__ __launch_bounds__(256)
void sd_k(const float* __restrict__ hfeat, const float* __restrict__ a_src,
          const float* __restrict__ a_dst, float* __restrict__ s,
          float* __restrict__ d, int n) {
    const int lane = threadIdx.x & 63;
    const int node = blockIdx.x * 4 + (threadIdx.x >> 6);
    if (node >= n) return;
    const float* row = hfeat + (size_t)node * (H * 64);
    #pragma unroll
    for (int h = 0; h < H; ++h) {
        float f = row[h * 64 + lane];
        float vs = f * a_src[h * 64 + lane];
        float vd = f * a_dst[h * 64 + lane];
        #pragma unroll
        for (int m = 32; m; m >>= 1) {
            vs += __shfl_xor(vs, m);
            vd += __shfl_xor(vd, m);
        }
        if (lane == 0) { s[node * H + h] = vs; d[node * H + h] = vd; }
    }
}

// ---------------------------------------------------------------------------
__device__ __forceinline__ float leaky(float e) { return (e > 0.f) ? e : 0.2f * e; }

__device__ __forceinline__ float sel4(const float v[4], int idx) {
    float r = v[0];
    r = (idx == 1) ? v[1] : r;
    r = (idx == 2) ? v[2] : r;
    r = (idx == 3) ? v[3] : r;
    return r;
}

// online softmax accumulate: (m, sm) <- merge with value e
__device__ __forceinline__ void osm_upd(float& m, float& sm, float e) {
    float nm = fmaxf(m, e);
    sm = sm * __expf(m - nm) + __expf(e - nm);
    m = nm;
}

// GAT attention + aggregation, one wave per dst node. out = relu(agg + bias).
// EB: pass1 stores e[E*H] + online (m,sum); pass3 gathers fp16 h rows.
// !EB fallback: 3-pass fp32 recompute (no extra workspace).
template<int H, bool EB>
__global__ __launch_bounds__(256)
void agg_k(const float* __restrict__ hfeat, const _Float16* __restrict__ hhalf,
           const float* __restrict__ s, const float* __restrict__ d,
           const float* __restrict__ bias, const int* __restrict__ rowptr,
           const int* __restrict__ csr_src, float* __restrict__ ebuf,
           float* __restrict__ out, int n) {
    const int lane = threadIdx.x & 63;
    const int node = blockIdx.x * 4 + (threadIdx.x >> 6);
    if (node >= n) return;
    const int beg = rowptr[node];
    const int end = rowptr[node + 1];
    float dh[H], mx[H], sm[H], inv[H];
    #pragma unroll
    for (int h = 0; h < H; ++h) {
        dh[h] = d[node * H + h];
        mx[h] = -3.0e38f; sm[h] = 0.f;
    }
    // pass 1: e = leaky(s[src]+d[dst]); online max+sum; EB: store e
    for (int i = beg + lane; i < end; i += 64) {
        int sidx = csr_src[i];
        if constexpr (H == 4) {
            float4 sv = *(const float4*)(s + (size_t)sidx * 4);
            float4 e;
            e.x = leaky(sv.x + dh[0]); e.y = leaky(sv.y + dh[1]);
            e.z = leaky(sv.z + dh[2]); e.w = leaky(sv.w + dh[3]);
            if (EB) *(float4*)(ebuf + (size_t)i * 4) = e;
            osm_upd(mx[0], sm[0], e.x); osm_upd(mx[1], sm[1], e.y);
            osm_upd(mx[2], sm[2], e.z); osm_upd(mx[3], sm[3], e.w);
        } else {
            float e = leaky(s[sidx] + dh[0]);
            if (EB) ebuf[i] = e;
            osm_upd(mx[0], sm[0], e);
        }
    }
    // cross-lane online merge
    #pragma unroll
    for (int h = 0; h < H; ++h) {
        #pragma unroll
        for (int dd = 32; dd; dd >>= 1) {
            float om = __shfl_xor(mx[h], dd);
            float os = __shfl_xor(sm[h], dd);
            float nm = fmaxf(mx[h], om);
            sm[h] = sm[h] * __expf(mx[h] - nm) + os * __expf(om - nm);
            mx[h] = nm;
        }
        inv[h] = 1.f / (sm[h] + 1e-16f);
    }
    // pass 3: aggregate alpha * h[src]
    if constexpr (H == 4) {
        const int head = lane >> 4;
        const float invh = sel4(inv, head);
        const float mxh = sel4(mx, head);
        const float dhh = sel4(dh, head);
        float4 acc = {0.f, 0.f, 0.f, 0.f};
        int i = beg;
        if constexpr (EB) {
            const half4* H4 = (const half4*)hhalf;  // row = 64 half4
            for (; i + 1 < end; i += 2) {
                int s0 = csr_src[i], s1 = csr_src[i + 1];
                float al0 = __expf(ebuf[(size_t)i * 4 + head] - mxh) * invh;
                float al1 = __expf(ebuf[(size_t)(i + 1) * 4 + head] - mxh) * invh;
                half4 h0 = H4[(size_t)s0 * 64 + lane];
                half4 h1 = H4[(size_t)s1 * 64 + lane];
                acc.x += al0 * (float)h0.x + al1 * (float)h1.x;
                acc.y += al0 * (float)h0.y + al1 * (float)h1.y;
                acc.z += al0 * (float)h0.z + al1 * (float)h1.z;
                acc.w += al0 * (float)h0.w + al1 * (float)h1.w;
            }
            if (i < end) {
                int s0 = csr_src[i];
                float al0 = __expf(ebuf[(size_t)i * 4 + head] - mxh) * invh;
                half4 h0 = H4[(size_t)s0 * 64 + lane];
                acc.x += al0 * (float)h0.x; acc.y += al0 * (float)h0.y;
                acc.z += al0 * (float)h0.z; acc.w += al0 * (float)h0.w;
            }
        } else {
            const float4* H4 = (const float4*)hfeat;
            for (; i < end; ++i) {
                int s0 = csr_src[i];
                float al0 = __expf(leaky(s[(size_t)s0 * 4 + head] + dhh) - mxh) * invh;
                float4 h0 = H4[(size_t)s0 * 64 + lane];
                acc.x += al0 * h0.x; acc.y += al0 * h0.y;
                acc.z += al0 * h0.z; acc.w += al0 * h0.w;
            }
        }
        float4 bv = ((const float4*)bias)[lane];
        float4 o;
        o.x = fmaxf(acc.x + bv.x, 0.f); o.y = fmaxf(acc.y + bv.y, 0.f);
        o.z = fmaxf(acc.z + bv.z, 0.f); o.w = fmaxf(acc.w + bv.w, 0.f);
        ((float4*)out)[(size_t)node * 64 + lane] = o;
    } else {
        const float invh = inv[0];
        float acc = 0.f;
        int i = beg;
        if constexpr (EB) {
            for (; i + 3 < end; i += 4) {
                int s0 = csr_src[i], s1 = csr_src[i + 1];
                int s2 = csr_src[i + 2], s3 = csr_src[i + 3];
                float a0 = __expf(ebuf[i] - mx[0]) * invh;
                float a1 = __expf(ebuf[i + 1] - mx[0]) * invh;
                float a2 = __expf(ebuf[i + 2] - mx[0]) * invh;
                float a3 = __expf(ebuf[i + 3] - mx[0]) * invh;
                acc += a0 * (float)hhalf[(size_t)s0 * 64 + lane];
                acc += a1 * (float)hhalf[(size_t)s1 * 64 + lane];
                acc += a2 * (float)hhalf[(size_t)s2 * 64 + lane];
                acc += a3 * (float)hhalf[(size_t)s3 * 64 + lane];
            }
            for (; i < end; ++i) {
                int s0 = csr_src[i];
                float a0 = __expf(ebuf[i] - mx[0]) * invh;
                acc += a0 * (float)hhalf[(size_t)s0 * 64 + lane];
            }
        } else {
            for (; i < end; ++i) {
                int s0 = csr_src[i];
                float a0 = __expf(leaky(s[s0] + dh[0]) - mx[0]) * invh;
                acc += a0 * hfeat[(size_t)s0 * 64 + lane];
            }
        }
        float v = acc + bias[lane];
        out[(size_t)node * 64 + lane] = fmaxf(v, 0.f);
    }
}

// ---------------------------------------------------------------------------
// Fused FF: out = softmax(relu(in@Wf1+bf1)@Wf2+bf2). Wave per node, weights in LDS.
__global__ __launch_bounds__(256)
void ff_k(const float* __restrict__ in, const float* __restrict__ Wf1,
          const float* __restrict__ bf1, const float* __restrict__ Wf2,
          const float* __restrict__ bf2, float* __restrict__ out, int n) {
    __shared__ float w1[64 * 64];
    __shared__ float w2[64 * 64];
    __shared__ float xrow[4][64];
    __shared__ float yrow[4][64];
    const int tid = threadIdx.x;
    for (int i = tid; i < 64 * 64; i += 256) { w1[i] = Wf1[i]; w2[i] = Wf2[i]; }
    const int wv = tid >> 6;
    const int lane = tid & 63;
    const int node = blockIdx.x * 4 + wv;
    const int nd = node < n ? node : (n - 1);
    float x = in[(size_t)nd * 64 + lane];
    xrow[wv][lane] = x;
    __syncthreads();
    float y = bf1[lane];
    #pragma unroll 8
    for (int k = 0; k < 64; ++k) y += xrow[wv][k] * w1[k * 64 + lane];
    y = fmaxf(y, 0.f);
    yrow[wv][lane] = y;
    __syncthreads();
    float z = bf2[lane];
    #pragma unroll 8
    for (int k = 0; k < 64; ++k) z += yrow[wv][k] * w2[k * 64 + lane];
    float m = z;
    #pragma unroll
    for (int dd = 32; dd; dd >>= 1) m = fmaxf(m, __shfl_xor(m, dd));
    float ex = __expf(z - m);
    float sum = ex;
    #pragma unroll
    for (int dd = 32; dd; dd >>= 1) sum += __shfl_xor(sum, dd);
    if (node < n) out[(size_t)node * 64 + lane] = ex / sum;
}

// ---------------------------------------------------------------------------
extern "C" void kernel_launch(void* const* d_in, const int* in_sizes, int n_in,
                              void* d_out, int out_size, void* d_ws, size_t ws_size,
                              hipStream_t stream) {
    const float* x      = (const float*)d_in[0];
    const void*  ei     = d_in[1];
    const float* W1     = (const float*)d_in[2];
    const float* a_src1 = (const float*)d_in[3];
    const float* a_dst1 = (const float*)d_in[4];
    const float* b1     = (const float*)d_in[5];
    const float* W2     = (const float*)d_in[6];
    const float* a_src2 = (const float*)d_in[7];
    const float* a_dst2 = (const float*)d_in[8];
    const float* b2     = (const float*)d_in[9];
    const float* Wf1    = (const float*)d_in[10];
    const float* bf1    = (const float*)d_in[11];
    const float* Wf2    = (const float*)d_in[12];
    const float* bf2    = (const float*)d_in[13];
    float* outp = (float*)d_out;

    // workspace carve-up (256B aligned)
    char* ws = (char*)d_ws;
    size_t off = 0;
    auto take = [&](size_t bytes) -> char* {
        char* p = ws + off;
        off += (bytes + 255) & ~(size_t)255;
        return p;
    };
    int*   flag   = (int*)take(4);
    int*   count  = (int*)take((size_t)NNODES * 4);
    int*   fill   = (int*)take((size_t)NNODES * 4);
    int*   rowptr = (int*)take((size_t)(NNODES + 1) * 4);
    int*   csr    = (int*)take((size_t)ETOT * 4);
    float* h1     = (float*)take((size_t)NNODES * 256 * 4);
    float* agg1   = (float*)take((size_t)NNODES * 256 * 4);
    float* s1     = (float*)take((size_t)NNODES * HEADS * 4);
    float* d1     = (float*)take((size_t)NNODES * HEADS * 4);
    float* ebuf   = (float*)take((size_t)ETOT * HEADS * 4);
    _Float16* h1h = (_Float16*)take((size_t)NNODES * 256 * 2);
    const bool eb_ok = (off <= ws_size);
    // reuse dead buffers for layer 2
    float*    h2   = h1;    // h1 dead after agg1
    float*    s2   = s1;
    float*    d2   = d1;
    float*    agg2 = agg1;  // agg1 dead after gemm2
    _Float16* h2h  = h1h;   // h1h dead after agg1

    // CSR build (shared by both GAT layers)
    detect_k<<<1, 1, 0, stream>>>((const unsigned*)ei, flag);
    hipMemsetAsync(count, 0, (size_t)NNODES * 4, stream);
    hipMemsetAsync(fill, 0, (size_t)NNODES * 4, stream);
    const int eblocks = (ETOT + 255) / 256;
    hist_k<<<eblocks, 256, 0, stream>>>(ei, flag, count);
    scan_k<<<1, 1024, 0, stream>>>(count, rowptr, NNODES);
    scatter_k<<<eblocks, 256, 0, stream>>>(ei, flag, rowptr, fill, csr);

    const int nodeblocks = NNODES / 4;  // 12500, exact
    const dim3 gg1(256 / 128, (NNODES + 127) / 128);
    const dim3 gg2(64 / 64, (NNODES + 127) / 128);

    // Layer 1: h1 = x@W1 (fp32 + fp16 copy); s,d; attention+aggregate
    gemm128_k<<<gg1, 256, 0, stream>>>(x, W1, h1, eb_ok ? h1h : nullptr, NNODES, 256, 256);
    sd_k<HEADS><<<nodeblocks, 256, 0, stream>>>(h1, a_src1, a_dst1, s1, d1, NNODES);
    if (eb_ok)
        agg_k<HEADS, true><<<nodeblocks, 256, 0, stream>>>(h1, h1h, s1, d1, b1, rowptr, csr, ebuf, agg1, NNODES);
    else
        agg_k<HEADS, false><<<nodeblocks, 256, 0, stream>>>(h1, h1h, s1, d1, b1, rowptr, csr, ebuf, agg1, NNODES);

    // Layer 2: h2 = agg1@W2; s,d; attention+aggregate
    gemm64_k<<<gg2, 256, 0, stream>>>(agg1, W2, h2, eb_ok ? h2h : nullptr, NNODES, 64, 256);
    sd_k<1><<<nodeblocks, 256, 0, stream>>>(h2, a_src2, a_dst2, s2, d2, NNODES);
    if (eb_ok)
        agg_k<1, true><<<nodeblocks, 256, 0, stream>>>(h2, h2h, s2, d2, b2, rowptr, csr, ebuf, agg2, NNODES);
    else
        agg_k<1, false><<<nodeblocks, 256, 0, stream>>>(h2, h2h, s2, d2, b2, rowptr, csr, ebuf, agg2, NNODES);

    // FF + softmax
    ff_k<<<nodeblocks, 256, 0, stream>>>(agg2, Wf1, bf1, Wf2, bf2, outp, NNODES);
}

// Round 4
// 379.415 us; speedup vs baseline: 1.5826x; 1.3083x over previous
//
#include <hip/hip_runtime.h>

// Problem constants (from reference)
#define NNODES 50000
#define NEDGES 800000
#define INDIM  256
#define HIDC   64
#define HEADS  4
static constexpr int ETOT = NEDGES + NNODES;  // edges + self loops

typedef _Float16 half4 __attribute__((ext_vector_type(4)));
typedef short    s16x8 __attribute__((ext_vector_type(8)));   // 8 bf16 (4 VGPR) MFMA frag
typedef short    s16x4 __attribute__((ext_vector_type(4)));
typedef float    f32x4 __attribute__((ext_vector_type(4)));   // MFMA accumulator

// bf16 helpers (RNE)
__device__ __forceinline__ unsigned short f2bf(float f) {
    unsigned u = __float_as_uint(f);
    u += 0x7fffu + ((u >> 16) & 1u);
    return (unsigned short)(u >> 16);
}
__device__ __forceinline__ float bf2f(unsigned short h) {
    return __uint_as_float(((unsigned)h) << 16);
}

// ---------------------------------------------------------------------------
// edge_index element-width detection (parallel): int64 => odd 32-bit words zero
__global__ void detect_k(const unsigned* __restrict__ ei32, int* __restrict__ flag) {
    __shared__ int any32;
    if (threadIdx.x == 0) any32 = 0;
    __syncthreads();
    if (ei32[1 + 2 * threadIdx.x] != 0u) any32 = 1;
    __syncthreads();
    if (threadIdx.x == 0) *flag = !any32;
}

__device__ __forceinline__ int load_idx(const void* ei, int is64, size_t pos) {
    return is64 ? (int)((const long long*)ei)[pos] : ((const int*)ei)[pos];
}

// ---------------------------------------------------------------------------
// CSR build: histogram of dst, two-level exclusive scan, scatter src ids
__global__ __launch_bounds__(256)
void hist_k(const void* __restrict__ ei, const int* __restrict__ flag,
            int* __restrict__ count) {
    int e = blockIdx.x * 256 + threadIdx.x;
    if (e >= ETOT) return;
    int is64 = *flag;
    int dst = (e < NEDGES) ? load_idx(ei, is64, (size_t)NEDGES + e) : (e - NEDGES);
    atomicAdd(&count[dst], 1);
}

// per-block exclusive scan of count -> rowptr (block-local), block sums -> bsum
__global__ __launch_bounds__(1024)
void scan1_k(const int* __restrict__ count, int* __restrict__ rowptr,
             int* __restrict__ bsum, int n) {
    __shared__ int wsum[16];
    const int tid = threadIdx.x;
    const int lane = tid & 63;
    const int w = tid >> 6;
    int i = blockIdx.x * 1024 + tid;
    int v = (i < n) ? count[i] : 0;
    int x = v;
    #pragma unroll
    for (int dd = 1; dd < 64; dd <<= 1) {
        int y = __shfl_up(x, dd);
        if (lane >= dd) x += y;
    }
    if (lane == 63) wsum[w] = x;
    __syncthreads();
    int woff = 0, total = 0;
    #pragma unroll
    for (int j = 0; j < 16; ++j) {
        if (j < w) woff += wsum[j];
        total += wsum[j];
    }
    if (i < n) rowptr[i] = woff + x - v;
    if (tid == 0) bsum[blockIdx.x] = total;
}

// scan of <=64 block sums (exclusive) in one wave
__global__ void scan2_k(int* __restrict__ bsum, int* __restrict__ bpre, int nb,
                        int* __restrict__ rowptr, int n) {
    int lane = threadIdx.x;
    int v = (lane < nb) ? bsum[lane] : 0;
    int x = v;
    #pragma unroll
    for (int dd = 1; dd < 64; dd <<= 1) {
        int y = __shfl_up(x, dd);
        if (lane >= dd) x += y;
    }
    if (lane < nb) bpre[lane] = x - v;
    if (lane == 63) rowptr[n] = x;  // grand total
}

__global__ __launch_bounds__(1024)
void scan3_k(int* __restrict__ rowptr, const int* __restrict__ bpre, int n) {
    int i = blockIdx.x * 1024 + threadIdx.x;
    if (i < n) rowptr[i] += bpre[blockIdx.x];
}

__global__ __launch_bounds__(256)
void scatter_k(const void* __restrict__ ei, const int* __restrict__ flag,
               const int* __restrict__ rowptr, int* __restrict__ fill,
               int* __restrict__ csr_src) {
    int e = blockIdx.x * 256 + threadIdx.x;
    if (e >= ETOT) return;
    int is64 = *flag;
    int src, dst;
    if (e < NEDGES) {
        src = load_idx(ei, is64, (size_t)e);
        dst = load_idx(ei, is64, (size_t)NEDGES + e);
    } else {
        src = e - NEDGES; dst = src;
    }
    int pos = rowptr[dst] + atomicAdd(&fill[dst], 1);
    csr_src[pos] = src;
}

// ---------------------------------------------------------------------------
// Weight pre-convert: W[K][N] fp32 -> Bt_hi/Bt_lo[N][K] bf16 (transposed)
__global__ __launch_bounds__(256)
void convw_k(const float* __restrict__ W, unsigned short* __restrict__ t_hi,
             unsigned short* __restrict__ t_lo, int K, int N) {
    int idx = blockIdx.x * 256 + threadIdx.x;
    if (idx >= K * N) return;
    int k = idx / N, n = idx % N;
    float w = W[idx];
    unsigned short hi = f2bf(w);
    unsigned short lo = f2bf(w - bf2f(hi));
    t_hi[(size_t)n * K + k] = hi;
    t_lo[(size_t)n * K + k] = lo;
}

// ---------------------------------------------------------------------------
// Split-bf16 MFMA GEMM: C[M,N] = A[M,K]@B[K,N], A fp32 (converted in staging),
// B pre-converted/transposed bf16 hi/lo. BM=128, BK=32, 256 thr, waves 2x2.
// C ~= Ah*Bh + Ah*Bl + Al*Bh  (rel err ~2^-16). Ch: optional fp16 copy.
template<int BN>
__global__ __launch_bounds__(256)
void gemm_mfma_k(const float* __restrict__ A,
                 const unsigned short* __restrict__ Bt_hi,
                 const unsigned short* __restrict__ Bt_lo,
                 float* __restrict__ C, _Float16* __restrict__ Ch,
                 int M, int N, int K) {
    constexpr int CB = BN / 32;          // 16-col frags per wave
    constexpr int BI = (BN * 4) / 256;   // B 16B-chunks per thread per half
    __shared__ unsigned short sAh[128][40], sAl[128][40];  // pad 40 (80B rows)
    __shared__ unsigned short sBh[BN][40], sBl[BN][40];
    const int tid = threadIdx.x;
    const int bm = blockIdx.y * 128;
    const int bn = blockIdx.x * BN;
    const int w = tid >> 6, lane = tid & 63;
    const int wr = w >> 1, wc = w & 1;
    const int lr = lane & 15, lk = lane >> 4;

    f32x4 acc[4][CB] = {};

    for (int k0 = 0; k0 < K; k0 += 32) {
        // global loads (A fp32 tile 128x32; B bf16 chunks)
        float4 av[4];
        #pragma unroll
        for (int i = 0; i < 4; ++i) {
            int idx = tid + 256 * i;
            int row = idx >> 3, c4 = idx & 7;
            int grow = bm + row; if (grow >= M) grow = M - 1;
            av[i] = *(const float4*)(A + (size_t)grow * K + k0 + c4 * 4);
        }
        s16x8 bhv[BI], blv[BI];
        #pragma unroll
        for (int i = 0; i < BI; ++i) {
            int idx = tid + 256 * i;
            int col = idx >> 2, ch = idx & 3;
            bhv[i] = *(const s16x8*)(Bt_hi + (size_t)(bn + col) * K + k0 + ch * 8);
            blv[i] = *(const s16x8*)(Bt_lo + (size_t)(bn + col) * K + k0 + ch * 8);
        }
        __syncthreads();
        #pragma unroll
        for (int i = 0; i < 4; ++i) {
            int idx = tid + 256 * i;
            int row = idx >> 3, c4 = idx & 7;
            float vs[4] = {av[i].x, av[i].y, av[i].z, av[i].w};
            unsigned short h[4], l[4];
            #pragma unroll
            for (int j = 0; j < 4; ++j) {
                h[j] = f2bf(vs[j]);
                l[j] = f2bf(vs[j] - bf2f(h[j]));
            }
            *(s16x4*)&sAh[row][c4 * 4] = (s16x4){(short)h[0], (short)h[1], (short)h[2], (short)h[3]};
            *(s16x4*)&sAl[row][c4 * 4] = (s16x4){(short)l[0], (short)l[1], (short)l[2], (short)l[3]};
        }
        #pragma unroll
        for (int i = 0; i < BI; ++i) {
            int idx = tid + 256 * i;
            int col = idx >> 2, ch = idx & 3;
            *(s16x8*)&sBh[col][ch * 8] = bhv[i];
            *(s16x8*)&sBl[col][ch * 8] = blv[i];
        }
        __syncthreads();
        // fragment loads + 3-term MFMA
        s16x8 afh[4], afl[4], bfh[CB], bfl[CB];
        #pragma unroll
        for (int rb = 0; rb < 4; ++rb) {
            int row = wr * 64 + rb * 16 + lr;
            afh[rb] = *(const s16x8*)&sAh[row][lk * 8];
            afl[rb] = *(const s16x8*)&sAl[row][lk * 8];
        }
        #pragma unroll
        for (int cb = 0; cb < CB; ++cb) {
            int col = wc * (BN / 2) + cb * 16 + lr;
            bfh[cb] = *(const s16x8*)&sBh[col][lk * 8];
            bfl[cb] = *(const s16x8*)&sBl[col][lk * 8];
        }
        #pragma unroll
        for (int rb = 0; rb < 4; ++rb)
            #pragma unroll
            for (int cb = 0; cb < CB; ++cb) {
                acc[rb][cb] = __builtin_amdgcn_mfma_f32_16x16x32_bf16(afh[rb], bfh[cb], acc[rb][cb], 0, 0, 0);
                acc[rb][cb] = __builtin_amdgcn_mfma_f32_16x16x32_bf16(afh[rb], bfl[cb], acc[rb][cb], 0, 0, 0);
                acc[rb][cb] = __builtin_amdgcn_mfma_f32_16x16x32_bf16(afl[rb], bfh[cb], acc[rb][cb], 0, 0, 0);
            }
    }
    // epilogue: C/D layout col=lane&15, row=(lane>>4)*4+r  [m89-verified]
    #pragma unroll
    for (int rb = 0; rb < 4; ++rb)
        #pragma unroll
        for (int cb = 0; cb < CB; ++cb)
            #pragma unroll
            for (int r = 0; r < 4; ++r) {
                int row = bm + wr * 64 + rb * 16 + lk * 4 + r;
                int col = bn + wc * (BN / 2) + cb * 16 + lr;
                if (row < M) {
                    float v = acc[rb][cb][r];
                    C[(size_t)row * N + col] = v;
                    if (Ch) Ch[(size_t)row * N + col] = (_Float16)v;
                }
            }
}

// ---------------------------------------------------------------------------
// s[n,h] = sum_c h[n,h,c]*a_src[h,c]; d likewise. One wave per node.
template<int H>
__global__ __launch_bounds__(256)
void sd_k(const float* __restrict__ hfeat, const float* __restrict__ a_src,
          const float* __restrict__ a_dst, float* __restrict__ s,
          float* __restrict__ d, int n) {
    const int lane = threadIdx.x & 63;
    const int node = blockIdx.x * 4 + (threadIdx.x >> 6);
    if (node >= n) return;
    const float* row = hfeat + (size_t)node * (H * 64);
    #pragma unroll
    for (int h = 0; h < H; ++h) {
        float f = row[h * 64 + lane];
        float vs = f * a_src[h * 64 + lane];
        float vd = f * a_dst[h * 64 + lane];
        #pragma unroll
        for (int m = 32; m; m >>= 1) {
            vs += __shfl_xor(vs, m);
            vd += __shfl_xor(vd, m);
        }
        if (lane == 0) { s[node * H + h] = vs; d[node * H + h] = vd; }
    }
}

// ---------------------------------------------------------------------------
__device__ __forceinline__ float leaky(float e) { return (e > 0.f) ? e : 0.2f * e; }

__device__ __forceinline__ float sel4(const float v[4], int idx) {
    float r = v[0];
    r = (idx == 1) ? v[1] : r;
    r = (idx == 2) ? v[2] : r;
    r = (idx == 3) ? v[3] : r;
    return r;
}

__device__ __forceinline__ void osm_upd(float& m, float& sm, float e) {
    float nm = fmaxf(m, e);
    sm = sm * __expf(m - nm) + __expf(e - nm);
    m = nm;
}

// GAT attention + aggregation, one wave per dst node. out = relu(agg + bias).
template<int H, bool EB>
__global__ __launch_bounds__(256)
void agg_k(const float* __restrict__ hfeat, const _Float16* __restrict__ hhalf,
           const float* __restrict__ s, const float* __restrict__ d,
           const float* __restrict__ bias, const int* __restrict__ rowptr,
           const int* __restrict__ csr_src, float* __restrict__ ebuf,
           float* __restrict__ out, int n) {
    const int lane = threadIdx.x & 63;
    const int node = blockIdx.x * 4 + (threadIdx.x >> 6);
    if (node >= n) return;
    const int beg = rowptr[node];
    const int end = rowptr[node + 1];
    float dh[H], mx[H], sm[H], inv[H];
    #pragma unroll
    for (int h = 0; h < H; ++h) {
        dh[h] = d[node * H + h];
        mx[h] = -3.0e38f; sm[h] = 0.f;
    }
    for (int i = beg + lane; i < end; i += 64) {
        int sidx = csr_src[i];
        if constexpr (H == 4) {
            float4 sv = *(const float4*)(s + (size_t)sidx * 4);
            float4 e;
            e.x = leaky(sv.x + dh[0]); e.y = leaky(sv.y + dh[1]);
            e.z = leaky(sv.z + dh[2]); e.w = leaky(sv.w + dh[3]);
            if (EB) *(float4*)(ebuf + (size_t)i * 4) = e;
            osm_upd(mx[0], sm[0], e.x); osm_upd(mx[1], sm[1], e.y);
            osm_upd(mx[2], sm[2], e.z); osm_upd(mx[3], sm[3], e.w);
        } else {
            float e = leaky(s[sidx] + dh[0]);
            if (EB) ebuf[i] = e;
            osm_upd(mx[0], sm[0], e);
        }
    }
    #pragma unroll
    for (int h = 0; h < H; ++h) {
        #pragma unroll
        for (int dd = 32; dd; dd >>= 1) {
            float om = __shfl_xor(mx[h], dd);
            float os = __shfl_xor(sm[h], dd);
            float nm = fmaxf(mx[h], om);
            sm[h] = sm[h] * __expf(mx[h] - nm) + os * __expf(om - nm);
            mx[h] = nm;
        }
        inv[h] = 1.f / (sm[h] + 1e-16f);
    }
    if constexpr (H == 4) {
        const int head = lane >> 4;
        const float invh = sel4(inv, head);
        const float mxh = sel4(mx, head);
        const float dhh = sel4(dh, head);
        float4 acc = {0.f, 0.f, 0.f, 0.f};
        int i = beg;
        if constexpr (EB) {
            const half4* H4 = (const half4*)hhalf;
            for (; i + 1 < end; i += 2) {
                int s0 = csr_src[i], s1 = csr_src[i + 1];
                float al0 = __expf(ebuf[(size_t)i * 4 + head] - mxh) * invh;
                float al1 = __expf(ebuf[(size_t)(i + 1) * 4 + head] - mxh) * invh;
                half4 h0 = H4[(size_t)s0 * 64 + lane];
                half4 h1 = H4[(size_t)s1 * 64 + lane];
                acc.x += al0 * (float)h0.x + al1 * (float)h1.x;
                acc.y += al0 * (float)h0.y + al1 * (float)h1.y;
                acc.z += al0 * (float)h0.z + al1 * (float)h1.z;
                acc.w += al0 * (float)h0.w + al1 * (float)h1.w;
            }
            if (i < end) {
                int s0 = csr_src[i];
                float al0 = __expf(ebuf[(size_t)i * 4 + head] - mxh) * invh;
                half4 h0 = H4[(size_t)s0 * 64 + lane];
                acc.x += al0 * (float)h0.x; acc.y += al0 * (float)h0.y;
                acc.z += al0 * (float)h0.z; acc.w += al0 * (float)h0.w;
            }
        } else {
            const float4* H4 = (const float4*)hfeat;
            for (; i < end; ++i) {
                int s0 = csr_src[i];
                float al0 = __expf(leaky(s[(size_t)s0 * 4 + head] + dhh) - mxh) * invh;
                float4 h0 = H4[(size_t)s0 * 64 + lane];
                acc.x += al0 * h0.x; acc.y += al0 * h0.y;
                acc.z += al0 * h0.z; acc.w += al0 * h0.w;
            }
        }
        float4 bv = ((const float4*)bias)[lane];
        float4 o;
        o.x = fmaxf(acc.x + bv.x, 0.f); o.y = fmaxf(acc.y + bv.y, 0.f);
        o.z = fmaxf(acc.z + bv.z, 0.f); o.w = fmaxf(acc.w + bv.w, 0.f);
        ((float4*)out)[(size_t)node * 64 + lane] = o;
    } else {
        const float invh = inv[0];
        float acc = 0.f;
        int i = beg;
        if constexpr (EB) {
            for (; i + 3 < end; i += 4) {
                int s0 = csr_src[i], s1 = csr_src[i + 1];
                int s2 = csr_src[i + 2], s3 = csr_src[i + 3];
                float a0 = __expf(ebuf[i] - mx[0]) * invh;
                float a1 = __expf(ebuf[i + 1] - mx[0]) * invh;
                float a2 = __expf(ebuf[i + 2] - mx[0]) * invh;
                float a3 = __expf(ebuf[i + 3] - mx[0]) * invh;
                acc += a0 * (float)hhalf[(size_t)s0 * 64 + lane];
                acc += a1 * (float)hhalf[(size_t)s1 * 64 + lane];
                acc += a2 * (float)hhalf[(size_t)s2 * 64 + lane];
                acc += a3 * (float)hhalf[(size_t)s3 * 64 + lane];
            }
            for (; i < end; ++i) {
                int s0 = csr_src[i];
                float a0 = __expf(ebuf[i] - mx[0]) * invh;
                acc += a0 * (float)hhalf[(size_t)s0 * 64 + lane];
            }
        } else {
            for (; i < end; ++i) {
                int s0 = csr_src[i];
                float a0 = __expf(leaky(s[s0] + dh[0]) - mx[0]) * invh;
                acc += a0 * hfeat[(size_t)s0 * 64 + lane];
            }
        }
        float v = acc + bias[lane];
        out[(size_t)node * 64 + lane] = fmaxf(v, 0.f);
    }
}

// ---------------------------------------------------------------------------
// Fused FF: out = softmax(relu(in@Wf1+bf1)@Wf2+bf2). Grid-stride; weights in
// LDS once per block. xrow/yrow are wave-private (no cross-wave barrier).
__global__ __launch_bounds__(256)
void ff_k(const float* __restrict__ in, const float* __restrict__ Wf1,
          const float* __restrict__ bf1, const float* __restrict__ Wf2,
          const float* __restrict__ bf2, float* __restrict__ out, int n) {
    __shared__ float w1[64 * 64];
    __shared__ float w2[64 * 64];
    __shared__ float xrow[4][64];
    __shared__ float yrow[4][64];
    const int tid = threadIdx.x;
    for (int i = tid; i < 64 * 64; i += 256) { w1[i] = Wf1[i]; w2[i] = Wf2[i]; }
    __syncthreads();
    const int wv = tid >> 6;
    const int lane = tid & 63;
    const float B1 = bf1[lane], B2 = bf2[lane];
    const int nblk = (n + 3) / 4;
    for (int nb = blockIdx.x; nb < nblk; nb += gridDim.x) {
        int node = nb * 4 + wv;
        int nd = node < n ? node : (n - 1);
        float x = in[(size_t)nd * 64 + lane];
        xrow[wv][lane] = x;
        float y = B1;
        #pragma unroll 8
        for (int k = 0; k < 64; ++k) y += xrow[wv][k] * w1[k * 64 + lane];
        y = fmaxf(y, 0.f);
        yrow[wv][lane] = y;
        float z = B2;
        #pragma unroll 8
        for (int k = 0; k < 64; ++k) z += yrow[wv][k] * w2[k * 64 + lane];
        float m = z;
        #pragma unroll
        for (int dd = 32; dd; dd >>= 1) m = fmaxf(m, __shfl_xor(m, dd));
        float ex = __expf(z - m);
        float sum = ex;
        #pragma unroll
        for (int dd = 32; dd; dd >>= 1) sum += __shfl_xor(sum, dd);
        if (node < n) out[(size_t)node * 64 + lane] = ex / sum;
    }
}

// ---------------------------------------------------------------------------
extern "C" void kernel_launch(void* const* d_in, const int* in_sizes, int n_in,
                              void* d_out, int out_size, void* d_ws, size_t ws_size,
                              hipStream_t stream) {
    const float* x      = (const float*)d_in[0];
    const void*  ei     = d_in[1];
    const float* W1     = (const float*)d_in[2];
    const float* a_src1 = (const float*)d_in[3];
    const float* a_dst1 = (const float*)d_in[4];
    const float* b1     = (const float*)d_in[5];
    const float* W2     = (const float*)d_in[6];
    const float* a_src2 = (const float*)d_in[7];
    const float* a_dst2 = (const float*)d_in[8];
    const float* b2     = (const float*)d_in[9];
    const float* Wf1    = (const float*)d_in[10];
    const float* bf1    = (const float*)d_in[11];
    const float* Wf2    = (const float*)d_in[12];
    const float* bf2    = (const float*)d_in[13];
    float* outp = (float*)d_out;

    // workspace carve-up (256B aligned)
    char* ws = (char*)d_ws;
    size_t off = 0;
    auto take = [&](size_t bytes) -> char* {
        char* p = ws + off;
        off += (bytes + 255) & ~(size_t)255;
        return p;
    };
    int*   flag   = (int*)take(4);
    int*   count  = (int*)take((size_t)NNODES * 4);
    int*   fill   = (int*)take((size_t)NNODES * 4);
    int*   rowptr = (int*)take((size_t)(NNODES + 1) * 4);
    int*   bsum   = (int*)take(64 * 4);
    int*   bpre   = (int*)take(64 * 4);
    int*   csr    = (int*)take((size_t)ETOT * 4);
    unsigned short* w1t_hi = (unsigned short*)take((size_t)256 * 256 * 2);
    unsigned short* w1t_lo = (unsigned short*)take((size_t)256 * 256 * 2);
    unsigned short* w2t_hi = (unsigned short*)take((size_t)64 * 256 * 2);
    unsigned short* w2t_lo = (unsigned short*)take((size_t)64 * 256 * 2);
    float* h1     = (float*)take((size_t)NNODES * 256 * 4);
    float* agg1   = (float*)take((size_t)NNODES * 256 * 4);
    float* s1     = (float*)take((size_t)NNODES * HEADS * 4);
    float* d1     = (float*)take((size_t)NNODES * HEADS * 4);
    float* ebuf   = (float*)take((size_t)ETOT * HEADS * 4);
    _Float16* h1h = (_Float16*)take((size_t)NNODES * 256 * 2);
    const bool eb_ok = (off <= ws_size);
    // reuse dead buffers for layer 2
    float*    h2   = h1;
    float*    s2   = s1;
    float*    d2   = d1;
    float*    agg2 = agg1;
    _Float16* h2h  = h1h;

    // CSR build (shared by both GAT layers)
    detect_k<<<1, 128, 0, stream>>>((const unsigned*)ei, flag);
    hipMemsetAsync(count, 0, (size_t)NNODES * 4, stream);
    hipMemsetAsync(fill, 0, (size_t)NNODES * 4, stream);
    const int eblocks = (ETOT + 255) / 256;
    hist_k<<<eblocks, 256, 0, stream>>>(ei, flag, count);
    const int sblocks = (NNODES + 1023) / 1024;  // 49
    scan1_k<<<sblocks, 1024, 0, stream>>>(count, rowptr, bsum, NNODES);
    scan2_k<<<1, 64, 0, stream>>>(bsum, bpre, sblocks, rowptr, NNODES);
    scan3_k<<<sblocks, 1024, 0, stream>>>(rowptr, bpre, NNODES);
    scatter_k<<<eblocks, 256, 0, stream>>>(ei, flag, rowptr, fill, csr);

    // Weight pre-convert (tiny)
    convw_k<<<(256 * 256) / 256, 256, 0, stream>>>(W1, w1t_hi, w1t_lo, 256, 256);
    convw_k<<<(256 * 64) / 256, 256, 0, stream>>>(W2, w2t_hi, w2t_lo, 256, 64);

    const int nodeblocks = NNODES / 4;  // 12500
    const int mblocks = (NNODES + 127) / 128;  // 391
    const dim3 gg1(2, mblocks);   // N=256, BN=128
    const dim3 gg2(1, mblocks);   // N=64,  BN=64

    // Layer 1
    gemm_mfma_k<128><<<gg1, 256, 0, stream>>>(x, w1t_hi, w1t_lo, h1,
                                              eb_ok ? h1h : nullptr, NNODES, 256, 256);
    sd_k<HEADS><<<nodeblocks, 256, 0, stream>>>(h1, a_src1, a_dst1, s1, d1, NNODES);
    if (eb_ok)
        agg_k<HEADS, true><<<nodeblocks, 256, 0, stream>>>(h1, h1h, s1, d1, b1, rowptr, csr, ebuf, agg1, NNODES);
    else
        agg_k<HEADS, false><<<nodeblocks, 256, 0, stream>>>(h1, h1h, s1, d1, b1, rowptr, csr, ebuf, agg1, NNODES);

    // Layer 2
    gemm_mfma_k<64><<<gg2, 256, 0, stream>>>(agg1, w2t_hi, w2t_lo, h2,
                                             eb_ok ? h2h : nullptr, NNODES, 64, 256);
    sd_k<1><<<nodeblocks, 256, 0, stream>>>(h2, a_src2, a_dst2, s2, d2, NNODES);
    if (eb_ok)
        agg_k<1, true><<<nodeblocks, 256, 0, stream>>>(h2, h2h, s2, d2, b2, rowptr, csr, ebuf, agg2, NNODES);
    else
        agg_k<1, false><<<nodeblocks, 256, 0, stream>>>(h2, h2h, s2, d2, b2, rowptr, csr, ebuf, agg2, NNODES);

    // FF + softmax
    ff_k<<<1024, 256, 0, stream>>>(agg2, Wf1, bf1, Wf2, bf2, outp, NNODES);
}

// Round 5
// 376.298 us; speedup vs baseline: 1.5957x; 1.0083x over previous
//
#include <hip/hip_runtime.h>

// Problem constants (from reference)
#define NNODES 50000
#define NEDGES 800000
#define INDIM  256
#define HIDC   64
#define HEADS  4
static constexpr int ETOT = NEDGES + NNODES;  // edges + self loops

typedef _Float16 half4 __attribute__((ext_vector_type(4)));
typedef short    s16x8 __attribute__((ext_vector_type(8)));   // 8 bf16 (4 VGPR) MFMA frag
typedef short    s16x4 __attribute__((ext_vector_type(4)));
typedef float    f32x4 __attribute__((ext_vector_type(4)));   // MFMA accumulator

// bf16 helpers (RNE)
__device__ __forceinline__ unsigned short f2bf(float f) {
    unsigned u = __float_as_uint(f);
    u += 0x7fffu + ((u >> 16) & 1u);
    return (unsigned short)(u >> 16);
}
__device__ __forceinline__ float bf2f(unsigned short h) {
    return __uint_as_float(((unsigned)h) << 16);
}

// ---------------------------------------------------------------------------
// edge_index element-width detection (parallel): int64 => odd 32-bit words zero
__global__ void detect_k(const unsigned* __restrict__ ei32, int* __restrict__ flag) {
    __shared__ int any32;
    if (threadIdx.x == 0) any32 = 0;
    __syncthreads();
    if (ei32[1 + 2 * threadIdx.x] != 0u) any32 = 1;
    __syncthreads();
    if (threadIdx.x == 0) *flag = !any32;
}

__device__ __forceinline__ int load_idx(const void* ei, int is64, size_t pos) {
    return is64 ? (int)((const long long*)ei)[pos] : ((const int*)ei)[pos];
}

// ---------------------------------------------------------------------------
// CSR build: histogram of dst, two-level exclusive scan, scatter src ids
__global__ __launch_bounds__(256)
void hist_k(const void* __restrict__ ei, const int* __restrict__ flag,
            int* __restrict__ count) {
    int e = blockIdx.x * 256 + threadIdx.x;
    if (e >= ETOT) return;
    int is64 = *flag;
    int dst = (e < NEDGES) ? load_idx(ei, is64, (size_t)NEDGES + e) : (e - NEDGES);
    atomicAdd(&count[dst], 1);
}

// per-block exclusive scan of count -> rowptr (block-local), block sums -> bsum
__global__ __launch_bounds__(1024)
void scan1_k(const int* __restrict__ count, int* __restrict__ rowptr,
             int* __restrict__ bsum, int n) {
    __shared__ int wsum[16];
    const int tid = threadIdx.x;
    const int lane = tid & 63;
    const int w = tid >> 6;
    int i = blockIdx.x * 1024 + tid;
    int v = (i < n) ? count[i] : 0;
    int x = v;
    #pragma unroll
    for (int dd = 1; dd < 64; dd <<= 1) {
        int y = __shfl_up(x, dd);
        if (lane >= dd) x += y;
    }
    if (lane == 63) wsum[w] = x;
    __syncthreads();
    int woff = 0, total = 0;
    #pragma unroll
    for (int j = 0; j < 16; ++j) {
        if (j < w) woff += wsum[j];
        total += wsum[j];
    }
    if (i < n) rowptr[i] = woff + x - v;
    if (tid == 0) bsum[blockIdx.x] = total;
}

// scan of <=64 block sums (exclusive) in one wave
__global__ void scan2_k(int* __restrict__ bsum, int* __restrict__ bpre, int nb,
                        int* __restrict__ rowptr, int n) {
    int lane = threadIdx.x;
    int v = (lane < nb) ? bsum[lane] : 0;
    int x = v;
    #pragma unroll
    for (int dd = 1; dd < 64; dd <<= 1) {
        int y = __shfl_up(x, dd);
        if (lane >= dd) x += y;
    }
    if (lane < nb) bpre[lane] = x - v;
    if (lane == 63) rowptr[n] = x;  // grand total
}

__global__ __launch_bounds__(1024)
void scan3_k(int* __restrict__ rowptr, const int* __restrict__ bpre, int n) {
    int i = blockIdx.x * 1024 + threadIdx.x;
    if (i < n) rowptr[i] += bpre[blockIdx.x];
}

__global__ __launch_bounds__(256)
void scatter_k(const void* __restrict__ ei, const int* __restrict__ flag,
               const int* __restrict__ rowptr, int* __restrict__ fill,
               int* __restrict__ csr_src) {
    int e = blockIdx.x * 256 + threadIdx.x;
    if (e >= ETOT) return;
    int is64 = *flag;
    int src, dst;
    if (e < NEDGES) {
        src = load_idx(ei, is64, (size_t)e);
        dst = load_idx(ei, is64, (size_t)NEDGES + e);
    } else {
        src = e - NEDGES; dst = src;
    }
    int pos = rowptr[dst] + atomicAdd(&fill[dst], 1);
    csr_src[pos] = src;
}

// ---------------------------------------------------------------------------
// Weight pre-convert: W[K][N] fp32 -> Bt_hi/Bt_lo[N][K] bf16 (transposed)
__global__ __launch_bounds__(256)
void convw_k(const float* __restrict__ W, unsigned short* __restrict__ t_hi,
             unsigned short* __restrict__ t_lo, int K, int N) {
    int idx = blockIdx.x * 256 + threadIdx.x;
    if (idx >= K * N) return;
    int k = idx / N, n = idx % N;
    float w = W[idx];
    unsigned short hi = f2bf(w);
    unsigned short lo = f2bf(w - bf2f(hi));
    t_hi[(size_t)n * K + k] = hi;
    t_lo[(size_t)n * K + k] = lo;
}

// ---------------------------------------------------------------------------
// Split-bf16 MFMA GEMM: C[M,N] = A[M,K]@B[K,N], A fp32 (converted in staging),
// B pre-converted/transposed bf16 hi/lo. BM=128, BK=32, 256 thr, waves 2x2.
// C ~= Ah*Bh + Ah*Bl + Al*Bh  (rel err ~2^-16). Ch: optional fp16 copy.
template<int BN>
__global__ __launch_bounds__(256)
void gemm_mfma_k(const float* __restrict__ A,
                 const unsigned short* __restrict__ Bt_hi,
                 const unsigned short* __restrict__ Bt_lo,
                 float* __restrict__ C, _Float16* __restrict__ Ch,
                 int M, int N, int K) {
    constexpr int CB = BN / 32;          // 16-col frags per wave
    constexpr int BI = (BN * 4) / 256;   // B 16B-chunks per thread per half
    __shared__ unsigned short sAh[128][40], sAl[128][40];  // pad 40 (80B rows)
    __shared__ unsigned short sBh[BN][40], sBl[BN][40];
    const int tid = threadIdx.x;
    const int bm = blockIdx.y * 128;
    const int bn = blockIdx.x * BN;
    const int w = tid >> 6, lane = tid & 63;
    const int wr = w >> 1, wc = w & 1;
    const int lr = lane & 15, lk = lane >> 4;

    f32x4 acc[4][CB] = {};

    for (int k0 = 0; k0 < K; k0 += 32) {
        // global loads (A fp32 tile 128x32; B bf16 chunks)
        float4 av[4];
        #pragma unroll
        for (int i = 0; i < 4; ++i) {
            int idx = tid + 256 * i;
            int row = idx >> 3, c4 = idx & 7;
            int grow = bm + row; if (grow >= M) grow = M - 1;
            av[i] = *(const float4*)(A + (size_t)grow * K + k0 + c4 * 4);
        }
        s16x8 bhv[BI], blv[BI];
        #pragma unroll
        for (int i = 0; i < BI; ++i) {
            int idx = tid + 256 * i;
            int col = idx >> 2, ch = idx & 3;
            bhv[i] = *(const s16x8*)(Bt_hi + (size_t)(bn + col) * K + k0 + ch * 8);
            blv[i] = *(const s16x8*)(Bt_lo + (size_t)(bn + col) * K + k0 + ch * 8);
        }
        __syncthreads();
        #pragma unroll
        for (int i = 0; i < 4; ++i) {
            int idx = tid + 256 * i;
            int row = idx >> 3, c4 = idx & 7;
            float vs[4] = {av[i].x, av[i].y, av[i].z, av[i].w};
            unsigned short h[4], l[4];
            #pragma unroll
            for (int j = 0; j < 4; ++j) {
                h[j] = f2bf(vs[j]);
                l[j] = f2bf(vs[j] - bf2f(h[j]));
            }
            *(s16x4*)&sAh[row][c4 * 4] = (s16x4){(short)h[0], (short)h[1], (short)h[2], (short)h[3]};
            *(s16x4*)&sAl[row][c4 * 4] = (s16x4){(short)l[0], (short)l[1], (short)l[2], (short)l[3]};
        }
        #pragma unroll
        for (int i = 0; i < BI; ++i) {
            int idx = tid + 256 * i;
            int col = idx >> 2, ch = idx & 3;
            *(s16x8*)&sBh[col][ch * 8] = bhv[i];
            *(s16x8*)&sBl[col][ch * 8] = blv[i];
        }
        __syncthreads();
        // fragment loads + 3-term MFMA
        s16x8 afh[4], afl[4], bfh[CB], bfl[CB];
        #pragma unroll
        for (int rb = 0; rb < 4; ++rb) {
            int row = wr * 64 + rb * 16 + lr;
            afh[rb] = *(const s16x8*)&sAh[row][lk * 8];
            afl[rb] = *(const s16x8*)&sAl[row][lk * 8];
        }
        #pragma unroll
        for (int cb = 0; cb < CB; ++cb) {
            int col = wc * (BN / 2) + cb * 16 + lr;
            bfh[cb] = *(const s16x8*)&sBh[col][lk * 8];
            bfl[cb] = *(const s16x8*)&sBl[col][lk * 8];
        }
        #pragma unroll
        for (int rb = 0; rb < 4; ++rb)
            #pragma unroll
            for (int cb = 0; cb < CB; ++cb) {
                acc[rb][cb] = __builtin_amdgcn_mfma_f32_16x16x32_bf16(afh[rb], bfh[cb], acc[rb][cb], 0, 0, 0);
                acc[rb][cb] = __builtin_amdgcn_mfma_f32_16x16x32_bf16(afh[rb], bfl[cb], acc[rb][cb], 0, 0, 0);
                acc[rb][cb] = __builtin_amdgcn_mfma_f32_16x16x32_bf16(afl[rb], bfh[cb], acc[rb][cb], 0, 0, 0);
            }
    }
    // epilogue: C/D layout col=lane&15, row=(lane>>4)*4+r  [m89-verified]
    #pragma unroll
    for (int rb = 0; rb < 4; ++rb)
        #pragma unroll
        for (int cb = 0; cb < CB; ++cb)
            #pragma unroll
            for (int r = 0; r < 4; ++r) {
                int row = bm + wr * 64 + rb * 16 + lk * 4 + r;
                int col = bn + wc * (BN / 2) + cb * 16 + lr;
                if (row < M) {
                    float v = acc[rb][cb][r];
                    C[(size_t)row * N + col] = v;
                    if (Ch) Ch[(size_t)row * N + col] = (_Float16)v;
                }
            }
}

// ---------------------------------------------------------------------------
// s[n,h] = sum_c h[n,h,c]*a_src[h,c]; d likewise. One wave per node.
template<int H>
__global__ __launch_bounds__(256)
void sd_k(const float* __restrict__ hfeat, const float* __restrict__ a_src,
          const float* __restrict__ a_dst, float* __restrict__ s,
          float* __restrict__ d, int n) {
    const int lane = threadIdx.x & 63;
    const int node = blockIdx.x * 4 + (threadIdx.x >> 6);
    if (node >= n) return;
    const float* row = hfeat + (size_t)node * (H * 64);
    #pragma unroll
    for (int h = 0; h < H; ++h) {
        float f = row[h * 64 + lane];
        float vs = f * a_src[h * 64 + lane];
        float vd = f * a_dst[h * 64 + lane];
        #pragma unroll
        for (int m = 32; m; m >>= 1) {
            vs += __shfl_xor(vs, m);
            vd += __shfl_xor(vd, m);
        }
        if (lane == 0) { s[node * H + h] = vs; d[node * H + h] = vd; }
    }
}

// ---------------------------------------------------------------------------
__device__ __forceinline__ float leaky(float e) { return (e > 0.f) ? e : 0.2f * e; }

__device__ __forceinline__ float sel4(const float v[4], int idx) {
    float r = v[0];
    r = (idx == 1) ? v[1] : r;
    r = (idx == 2) ? v[2] : r;
    r = (idx == 3) ? v[3] : r;
    return r;
}

__device__ __forceinline__ void osm_upd(float& m, float& sm, float e) {
    float nm = fmaxf(m, e);
    sm = sm * __expf(m - nm) + __expf(e - nm);
    m = nm;
}

// GAT attention + aggregation, one wave per dst node. out = relu(agg + bias).
// EB path: pass1 e+max -> pass2 distributed exp+sum (ebuf holds ex) ->
// pass3 multiply-free gather-FMA; inv folded into epilogue.
template<int H, bool EB>
__global__ __launch_bounds__(256)
void agg_k(const float* __restrict__ hfeat, const _Float16* __restrict__ hhalf,
           const float* __restrict__ s, const float* __restrict__ d,
           const float* __restrict__ bias, const int* __restrict__ rowptr,
           const int* __restrict__ csr_src, float* __restrict__ ebuf,
           float* __restrict__ out, int n) {
    const int lane = threadIdx.x & 63;
    const int node = blockIdx.x * 4 + (threadIdx.x >> 6);
    if (node >= n) return;
    const int beg = rowptr[node];
    const int end = rowptr[node + 1];
    float dh[H], mx[H], dn[H], inv[H];
    #pragma unroll
    for (int h = 0; h < H; ++h) {
        dh[h] = d[node * H + h];
        mx[h] = -3.0e38f; dn[h] = 0.f;
    }

    if constexpr (EB) {
        // pass 1: e = leaky(s[src]+d[dst]) -> ebuf; plain max (no exp)
        for (int i = beg + lane; i < end; i += 64) {
            int sidx = csr_src[i];
            if constexpr (H == 4) {
                float4 sv = *(const float4*)(s + (size_t)sidx * 4);
                float4 e;
                e.x = leaky(sv.x + dh[0]); e.y = leaky(sv.y + dh[1]);
                e.z = leaky(sv.z + dh[2]); e.w = leaky(sv.w + dh[3]);
                *(float4*)(ebuf + (size_t)i * 4) = e;
                mx[0] = fmaxf(mx[0], e.x); mx[1] = fmaxf(mx[1], e.y);
                mx[2] = fmaxf(mx[2], e.z); mx[3] = fmaxf(mx[3], e.w);
            } else {
                float e = leaky(s[sidx] + dh[0]);
                ebuf[i] = e;
                mx[0] = fmaxf(mx[0], e);
            }
        }
        #pragma unroll
        for (int h = 0; h < H; ++h)
            #pragma unroll
            for (int m = 32; m; m >>= 1) mx[h] = fmaxf(mx[h], __shfl_xor(mx[h], m));

        // pass 2 (distributed): ex = exp(e - mx) -> ebuf; accumulate denom
        for (int i = beg + lane; i < end; i += 64) {
            if constexpr (H == 4) {
                float4 e = *(const float4*)(ebuf + (size_t)i * 4);
                float4 ex;
                ex.x = __expf(e.x - mx[0]); ex.y = __expf(e.y - mx[1]);
                ex.z = __expf(e.z - mx[2]); ex.w = __expf(e.w - mx[3]);
                *(float4*)(ebuf + (size_t)i * 4) = ex;
                dn[0] += ex.x; dn[1] += ex.y; dn[2] += ex.z; dn[3] += ex.w;
            } else {
                float ex = __expf(ebuf[i] - mx[0]);
                ebuf[i] = ex;
                dn[0] += ex;
            }
        }
        #pragma unroll
        for (int h = 0; h < H; ++h) {
            #pragma unroll
            for (int m = 32; m; m >>= 1) dn[h] += __shfl_xor(dn[h], m);
            inv[h] = 1.f / (dn[h] + 1e-16f);
        }

        // pass 3: acc += ex * h[src]  (no exp, no mul by inv)
        if constexpr (H == 4) {
            const int head = lane >> 4;
            const float invh = sel4(inv, head);
            const half4* H4 = (const half4*)hhalf;   // 64 half4 per row
            float4 acc = {0.f, 0.f, 0.f, 0.f};
            int i = beg;
            for (; i + 3 < end; i += 4) {
                int s0 = csr_src[i],     s1 = csr_src[i + 1];
                int s2 = csr_src[i + 2], s3 = csr_src[i + 3];
                float x0 = ebuf[(size_t)i * 4 + head];
                float x1 = ebuf[(size_t)(i + 1) * 4 + head];
                float x2 = ebuf[(size_t)(i + 2) * 4 + head];
                float x3 = ebuf[(size_t)(i + 3) * 4 + head];
                half4 h0 = H4[(size_t)s0 * 64 + lane];
                half4 h1 = H4[(size_t)s1 * 64 + lane];
                half4 h2 = H4[(size_t)s2 * 64 + lane];
                half4 h3 = H4[(size_t)s3 * 64 + lane];
                acc.x += x0 * (float)h0.x + x1 * (float)h1.x + x2 * (float)h2.x + x3 * (float)h3.x;
                acc.y += x0 * (float)h0.y + x1 * (float)h1.y + x2 * (float)h2.y + x3 * (float)h3.y;
                acc.z += x0 * (float)h0.z + x1 * (float)h1.z + x2 * (float)h2.z + x3 * (float)h3.z;
                acc.w += x0 * (float)h0.w + x1 * (float)h1.w + x2 * (float)h2.w + x3 * (float)h3.w;
            }
            for (; i < end; ++i) {
                int s0 = csr_src[i];
                float x0 = ebuf[(size_t)i * 4 + head];
                half4 h0 = H4[(size_t)s0 * 64 + lane];
                acc.x += x0 * (float)h0.x; acc.y += x0 * (float)h0.y;
                acc.z += x0 * (float)h0.z; acc.w += x0 * (float)h0.w;
            }
            float4 bv = ((const float4*)bias)[lane];
            float4 o;
            o.x = fmaxf(acc.x * invh + bv.x, 0.f); o.y = fmaxf(acc.y * invh + bv.y, 0.f);
            o.z = fmaxf(acc.z * invh + bv.z, 0.f); o.w = fmaxf(acc.w * invh + bv.w, 0.f);
            ((float4*)out)[(size_t)node * 64 + lane] = o;
        } else {
            // 16 lanes per edge, 4 edges in flight; half4 (8B) loads
            const int q = lane >> 4;     // edge offset 0..3
            const int c4 = lane & 15;    // 4-channel group
            const half4* H4 = (const half4*)hhalf;   // 16 half4 per row
            float4 acc = {0.f, 0.f, 0.f, 0.f};
            int i = beg;
            for (; i + 3 < end; i += 4) {
                int e = i + q;
                int s0 = csr_src[e];
                float x = ebuf[e];
                half4 hh = H4[(size_t)s0 * 16 + c4];
                acc.x += x * (float)hh.x; acc.y += x * (float)hh.y;
                acc.z += x * (float)hh.z; acc.w += x * (float)hh.w;
            }
            if (i + q < end) {
                int s0 = csr_src[i + q];
                float x = ebuf[i + q];
                half4 hh = H4[(size_t)s0 * 16 + c4];
                acc.x += x * (float)hh.x; acc.y += x * (float)hh.y;
                acc.z += x * (float)hh.z; acc.w += x * (float)hh.w;
            }
            #pragma unroll
            for (int m = 16; m <= 32; m <<= 1) {
                acc.x += __shfl_xor(acc.x, m); acc.y += __shfl_xor(acc.y, m);
                acc.z += __shfl_xor(acc.z, m); acc.w += __shfl_xor(acc.w, m);
            }
            if (lane < 16) {
                float4 bv = *(const float4*)(bias + c4 * 4);
                float4 o;
                o.x = fmaxf(acc.x * inv[0] + bv.x, 0.f);
                o.y = fmaxf(acc.y * inv[0] + bv.y, 0.f);
                o.z = fmaxf(acc.z * inv[0] + bv.z, 0.f);
                o.w = fmaxf(acc.w * inv[0] + bv.w, 0.f);
                *(float4*)(out + (size_t)node * 64 + c4 * 4) = o;
            }
        }
    } else {
        // fallback (no ebuf): online softmax + serial recompute, fp32 h
        float sm[H];
        #pragma unroll
        for (int h = 0; h < H; ++h) sm[h] = 0.f;
        for (int i = beg + lane; i < end; i += 64) {
            int sidx = csr_src[i];
            if constexpr (H == 4) {
                float4 sv = *(const float4*)(s + (size_t)sidx * 4);
                osm_upd(mx[0], sm[0], leaky(sv.x + dh[0]));
                osm_upd(mx[1], sm[1], leaky(sv.y + dh[1]));
                osm_upd(mx[2], sm[2], leaky(sv.z + dh[2]));
                osm_upd(mx[3], sm[3], leaky(sv.w + dh[3]));
            } else {
                osm_upd(mx[0], sm[0], leaky(s[sidx] + dh[0]));
            }
        }
        #pragma unroll
        for (int h = 0; h < H; ++h) {
            #pragma unroll
            for (int dd = 32; dd; dd >>= 1) {
                float om = __shfl_xor(mx[h], dd);
                float os = __shfl_xor(sm[h], dd);
                float nm = fmaxf(mx[h], om);
                sm[h] = sm[h] * __expf(mx[h] - nm) + os * __expf(om - nm);
                mx[h] = nm;
            }
            inv[h] = 1.f / (sm[h] + 1e-16f);
        }
        if constexpr (H == 4) {
            const int head = lane >> 4;
            const float invh = sel4(inv, head);
            const float mxh = sel4(mx, head);
            const float dhh = sel4(dh, head);
            const float4* H4 = (const float4*)hfeat;
            float4 acc = {0.f, 0.f, 0.f, 0.f};
            for (int i = beg; i < end; ++i) {
                int s0 = csr_src[i];
                float al0 = __expf(leaky(s[(size_t)s0 * 4 + head] + dhh) - mxh) * invh;
                float4 h0 = H4[(size_t)s0 * 64 + lane];
                acc.x += al0 * h0.x; acc.y += al0 * h0.y;
                acc.z += al0 * h0.z; acc.w += al0 * h0.w;
            }
            float4 bv = ((const float4*)bias)[lane];
            float4 o;
            o.x = fmaxf(acc.x + bv.x, 0.f); o.y = fmaxf(acc.y + bv.y, 0.f);
            o.z = fmaxf(acc.z + bv.z, 0.f); o.w = fmaxf(acc.w + bv.w, 0.f);
            ((float4*)out)[(size_t)node * 64 + lane] = o;
        } else {
            float acc = 0.f;
            for (int i = beg; i < end; ++i) {
                int s0 = csr_src[i];
                float a0 = __expf(leaky(s[s0] + dh[0]) - mx[0]) * inv[0];
                acc += a0 * hfeat[(size_t)s0 * 64 + lane];
            }
            float v = acc + bias[lane];
            out[(size_t)node * 64 + lane] = fmaxf(v, 0.f);
        }
    }
}

// ---------------------------------------------------------------------------
// Fused FF: out = softmax(relu(in@Wf1+bf1)@Wf2+bf2). Grid-stride; weights in
// LDS once per block. xrow/yrow are wave-private (no cross-wave barrier).
__global__ __launch_bounds__(256)
void ff_k(const float* __restrict__ in, const float* __restrict__ Wf1,
          const float* __restrict__ bf1, const float* __restrict__ Wf2,
          const float* __restrict__ bf2, float* __restrict__ out, int n) {
    __shared__ float w1[64 * 64];
    __shared__ float w2[64 * 64];
    __shared__ float xrow[4][64];
    __shared__ float yrow[4][64];
    const int tid = threadIdx.x;
    for (int i = tid; i < 64 * 64; i += 256) { w1[i] = Wf1[i]; w2[i] = Wf2[i]; }
    __syncthreads();
    const int wv = tid >> 6;
    const int lane = tid & 63;
    const float B1 = bf1[lane], B2 = bf2[lane];
    const int nblk = (n + 3) / 4;
    for (int nb = blockIdx.x; nb < nblk; nb += gridDim.x) {
        int node = nb * 4 + wv;
        int nd = node < n ? node : (n - 1);
        float x = in[(size_t)nd * 64 + lane];
        xrow[wv][lane] = x;
        float y = B1;
        #pragma unroll 8
        for (int k = 0; k < 64; ++k) y += xrow[wv][k] * w1[k * 64 + lane];
        y = fmaxf(y, 0.f);
        yrow[wv][lane] = y;
        float z = B2;
        #pragma unroll 8
        for (int k = 0; k < 64; ++k) z += yrow[wv][k] * w2[k * 64 + lane];
        float m = z;
        #pragma unroll
        for (int dd = 32; dd; dd >>= 1) m = fmaxf(m, __shfl_xor(m, dd));
        float ex = __expf(z - m);
        float sum = ex;
        #pragma unroll
        for (int dd = 32; dd; dd >>= 1) sum += __shfl_xor(sum, dd);
        if (node < n) out[(size_t)node * 64 + lane] = ex / sum;
    }
}

// ---------------------------------------------------------------------------
extern "C" void kernel_launch(void* const* d_in, const int* in_sizes, int n_in,
                              void* d_out, int out_size, void* d_ws, size_t ws_size,
                              hipStream_t stream) {
    const float* x      = (const float*)d_in[0];
    const void*  ei     = d_in[1];
    const float* W1     = (const float*)d_in[2];
    const float* a_src1 = (const float*)d_in[3];
    const float* a_dst1 = (const float*)d_in[4];
    const float* b1     = (const float*)d_in[5];
    const float* W2     = (const float*)d_in[6];
    const float* a_src2 = (const float*)d_in[7];
    const float* a_dst2 = (const float*)d_in[8];
    const float* b2     = (const float*)d_in[9];
    const float* Wf1    = (const float*)d_in[10];
    const float* bf1    = (const float*)d_in[11];
    const float* Wf2    = (const float*)d_in[12];
    const float* bf2    = (const float*)d_in[13];
    float* outp = (float*)d_out;

    // workspace carve-up (256B aligned)
    char* ws = (char*)d_ws;
    size_t off = 0;
    auto take = [&](size_t bytes) -> char* {
        char* p = ws + off;
        off += (bytes + 255) & ~(size_t)255;
        return p;
    };
    int*   flag   = (int*)take(4);
    int*   count  = (int*)take((size_t)NNODES * 4);
    int*   fill   = (int*)take((size_t)NNODES * 4);
    int*   rowptr = (int*)take((size_t)(NNODES + 1) * 4);
    int*   bsum   = (int*)take(64 * 4);
    int*   bpre   = (int*)take(64 * 4);
    int*   csr    = (int*)take((size_t)ETOT * 4);
    unsigned short* w1t_hi = (unsigned short*)take((size_t)256 * 256 * 2);
    unsigned short* w1t_lo = (unsigned short*)take((size_t)256 * 256 * 2);
    unsigned short* w2t_hi = (unsigned short*)take((size_t)64 * 256 * 2);
    unsigned short* w2t_lo = (unsigned short*)take((size_t)64 * 256 * 2);
    float* h1     = (float*)take((size_t)NNODES * 256 * 4);
    float* agg1   = (float*)take((size_t)NNODES * 256 * 4);
    float* s1     = (float*)take((size_t)NNODES * HEADS * 4);
    float* d1     = (float*)take((size_t)NNODES * HEADS * 4);
    float* ebuf   = (float*)take((size_t)ETOT * HEADS * 4);
    _Float16* h1h = (_Float16*)take((size_t)NNODES * 256 * 2);
    const bool eb_ok = (off <= ws_size);
    // reuse dead buffers for layer 2
    float*    h2   = h1;
    float*    s2   = s1;
    float*    d2   = d1;
    float*    agg2 = agg1;
    _Float16* h2h  = h1h;

    // CSR build (shared by both GAT layers)
    detect_k<<<1, 128, 0, stream>>>((const unsigned*)ei, flag);
    hipMemsetAsync(count, 0, (size_t)NNODES * 4, stream);
    hipMemsetAsync(fill, 0, (size_t)NNODES * 4, stream);
    const int eblocks = (ETOT + 255) / 256;
    hist_k<<<eblocks, 256, 0, stream>>>(ei, flag, count);
    const int sblocks = (NNODES + 1023) / 1024;  // 49
    scan1_k<<<sblocks, 1024, 0, stream>>>(count, rowptr, bsum, NNODES);
    scan2_k<<<1, 64, 0, stream>>>(bsum, bpre, sblocks, rowptr, NNODES);
    scan3_k<<<sblocks, 1024, 0, stream>>>(rowptr, bpre, NNODES);
    scatter_k<<<eblocks, 256, 0, stream>>>(ei, flag, rowptr, fill, csr);

    // Weight pre-convert (tiny)
    convw_k<<<(256 * 256) / 256, 256, 0, stream>>>(W1, w1t_hi, w1t_lo, 256, 256);
    convw_k<<<(256 * 64) / 256, 256, 0, stream>>>(W2, w2t_hi, w2t_lo, 256, 64);

    const int nodeblocks = NNODES / 4;  // 12500
    const int mblocks = (NNODES + 127) / 128;  // 391
    const dim3 gg1(2, mblocks);   // N=256, BN=128
    const dim3 gg2(1, mblocks);   // N=64,  BN=64

    // Layer 1
    gemm_mfma_k<128><<<gg1, 256, 0, stream>>>(x, w1t_hi, w1t_lo, h1,
                                              eb_ok ? h1h : nullptr, NNODES, 256, 256);
    sd_k<HEADS><<<nodeblocks, 256, 0, stream>>>(h1, a_src1, a_dst1, s1, d1, NNODES);
    if (eb_ok)
        agg_k<HEADS, true><<<nodeblocks, 256, 0, stream>>>(h1, h1h, s1, d1, b1, rowptr, csr, ebuf, agg1, NNODES);
    else
        agg_k<HEADS, false><<<nodeblocks, 256, 0, stream>>>(h1, h1h, s1, d1, b1, rowptr, csr, ebuf, agg1, NNODES);

    // Layer 2
    gemm_mfma_k<64><<<gg2, 256, 0, stream>>>(agg1, w2t_hi, w2t_lo, h2,
                                             eb_ok ? h2h : nullptr, NNODES, 64, 256);
    sd_k<1><<<nodeblocks, 256, 0, stream>>>(h2, a_src2, a_dst2, s2, d2, NNODES);
    if (eb_ok)
        agg_k<1, true><<<nodeblocks, 256, 0, stream>>>(h2, h2h, s2, d2, b2, rowptr, csr, ebuf, agg2, NNODES);
    else
        agg_k<1, false><<<nodeblocks, 256, 0, stream>>>(h2, h2h, s2, d2, b2, rowptr, csr, ebuf, agg2, NNODES);

    // FF + softmax
    ff_k<<<1024, 256, 0, stream>>>(agg2, Wf1, bf1, Wf2, bf2, outp, NNODES);
}

// Round 6
// 357.798 us; speedup vs baseline: 1.6782x; 1.0517x over previous
//
#include <hip/hip_runtime.h>

// Problem constants (from reference)
#define NNODES 50000
#define NEDGES 800000
#define INDIM  256
#define HIDC   64
#define HEADS  4
static constexpr int ETOT = NEDGES + NNODES;  // edges + self loops

typedef _Float16 half4 __attribute__((ext_vector_type(4)));
typedef _Float16 half8 __attribute__((ext_vector_type(8)));
typedef short    s16x8 __attribute__((ext_vector_type(8)));   // 8 bf16 (4 VGPR) MFMA frag
typedef short    s16x4 __attribute__((ext_vector_type(4)));
typedef float    f32x4 __attribute__((ext_vector_type(4)));   // MFMA accumulator

// bf16 helpers (RNE)
__device__ __forceinline__ unsigned short f2bf(float f) {
    unsigned u = __float_as_uint(f);
    u += 0x7fffu + ((u >> 16) & 1u);
    return (unsigned short)(u >> 16);
}
__device__ __forceinline__ float bf2f(unsigned short h) {
    return __uint_as_float(((unsigned)h) << 16);
}

// ---------------------------------------------------------------------------
// edge_index element-width detection (parallel): int64 => odd 32-bit words zero
__global__ void detect_k(const unsigned* __restrict__ ei32, int* __restrict__ flag) {
    __shared__ int any32;
    if (threadIdx.x == 0) any32 = 0;
    __syncthreads();
    if (ei32[1 + 2 * threadIdx.x] != 0u) any32 = 1;
    __syncthreads();
    if (threadIdx.x == 0) *flag = !any32;
}

__device__ __forceinline__ int load_idx(const void* ei, int is64, size_t pos) {
    return is64 ? (int)((const long long*)ei)[pos] : ((const int*)ei)[pos];
}

// ---------------------------------------------------------------------------
// CSR build: histogram of dst, two-level exclusive scan, scatter src ids
__global__ __launch_bounds__(256)
void hist_k(const void* __restrict__ ei, const int* __restrict__ flag,
            int* __restrict__ count) {
    int e = blockIdx.x * 256 + threadIdx.x;
    if (e >= ETOT) return;
    int is64 = *flag;
    int dst = (e < NEDGES) ? load_idx(ei, is64, (size_t)NEDGES + e) : (e - NEDGES);
    atomicAdd(&count[dst], 1);
}

// per-block exclusive scan of count -> rowptr (block-local), block sums -> bsum
__global__ __launch_bounds__(1024)
void scan1_k(const int* __restrict__ count, int* __restrict__ rowptr,
             int* __restrict__ bsum, int n) {
    __shared__ int wsum[16];
    const int tid = threadIdx.x;
    const int lane = tid & 63;
    const int w = tid >> 6;
    int i = blockIdx.x * 1024 + tid;
    int v = (i < n) ? count[i] : 0;
    int x = v;
    #pragma unroll
    for (int dd = 1; dd < 64; dd <<= 1) {
        int y = __shfl_up(x, dd);
        if (lane >= dd) x += y;
    }
    if (lane == 63) wsum[w] = x;
    __syncthreads();
    int woff = 0, total = 0;
    #pragma unroll
    for (int j = 0; j < 16; ++j) {
        if (j < w) woff += wsum[j];
        total += wsum[j];
    }
    if (i < n) rowptr[i] = woff + x - v;
    if (tid == 0) bsum[blockIdx.x] = total;
}

// scan of <=64 block sums (exclusive) in one wave
__global__ void scan2_k(int* __restrict__ bsum, int* __restrict__ bpre, int nb,
                        int* __restrict__ rowptr, int n) {
    int lane = threadIdx.x;
    int v = (lane < nb) ? bsum[lane] : 0;
    int x = v;
    #pragma unroll
    for (int dd = 1; dd < 64; dd <<= 1) {
        int y = __shfl_up(x, dd);
        if (lane >= dd) x += y;
    }
    if (lane < nb) bpre[lane] = x - v;
    if (lane == 63) rowptr[n] = x;  // grand total
}

__global__ __launch_bounds__(1024)
void scan3_k(int* __restrict__ rowptr, const int* __restrict__ bpre, int n) {
    int i = blockIdx.x * 1024 + threadIdx.x;
    if (i < n) rowptr[i] += bpre[blockIdx.x];
}

__global__ __launch_bounds__(256)
void scatter_k(const void* __restrict__ ei, const int* __restrict__ flag,
               const int* __restrict__ rowptr, int* __restrict__ fill,
               int* __restrict__ csr_src) {
    int e = blockIdx.x * 256 + threadIdx.x;
    if (e >= ETOT) return;
    int is64 = *flag;
    int src, dst;
    if (e < NEDGES) {
        src = load_idx(ei, is64, (size_t)e);
        dst = load_idx(ei, is64, (size_t)NEDGES + e);
    } else {
        src = e - NEDGES; dst = src;
    }
    int pos = rowptr[dst] + atomicAdd(&fill[dst], 1);
    csr_src[pos] = src;
}

// ---------------------------------------------------------------------------
// Weight pre-convert: W[K][N] fp32 -> Bt_hi/Bt_lo[N][K] bf16 (transposed)
__global__ __launch_bounds__(256)
void convw_k(const float* __restrict__ W, unsigned short* __restrict__ t_hi,
             unsigned short* __restrict__ t_lo, int K, int N) {
    int idx = blockIdx.x * 256 + threadIdx.x;
    if (idx >= K * N) return;
    int k = idx / N, n = idx % N;
    float w = W[idx];
    unsigned short hi = f2bf(w);
    unsigned short lo = f2bf(w - bf2f(hi));
    t_hi[(size_t)n * K + k] = hi;
    t_lo[(size_t)n * K + k] = lo;
}

// ---------------------------------------------------------------------------
// Split-bf16 MFMA GEMM: C[M,N] = A[M,K]@B[K,N], A fp32 (converted in staging),
// B pre-converted/transposed bf16 hi/lo. BM=128, BK=32, 256 thr, waves 2x2.
// C ~= Ah*Bh + Ah*Bl + Al*Bh  (rel err ~2^-16). Ch: optional fp16 copy.
template<int BN>
__global__ __launch_bounds__(256)
void gemm_mfma_k(const float* __restrict__ A,
                 const unsigned short* __restrict__ Bt_hi,
                 const unsigned short* __restrict__ Bt_lo,
                 float* __restrict__ C, _Float16* __restrict__ Ch,
                 int M, int N, int K) {
    constexpr int CB = BN / 32;          // 16-col frags per wave
    constexpr int BI = (BN * 4) / 256;   // B 16B-chunks per thread per half
    __shared__ unsigned short sAh[128][40], sAl[128][40];  // pad 40 (80B rows)
    __shared__ unsigned short sBh[BN][40], sBl[BN][40];
    const int tid = threadIdx.x;
    const int bm = blockIdx.y * 128;
    const int bn = blockIdx.x * BN;
    const int w = tid >> 6, lane = tid & 63;
    const int wr = w >> 1, wc = w & 1;
    const int lr = lane & 15, lk = lane >> 4;

    f32x4 acc[4][CB] = {};

    for (int k0 = 0; k0 < K; k0 += 32) {
        // global loads (A fp32 tile 128x32; B bf16 chunks)
        float4 av[4];
        #pragma unroll
        for (int i = 0; i < 4; ++i) {
            int idx = tid + 256 * i;
            int row = idx >> 3, c4 = idx & 7;
            int grow = bm + row; if (grow >= M) grow = M - 1;
            av[i] = *(const float4*)(A + (size_t)grow * K + k0 + c4 * 4);
        }
        s16x8 bhv[BI], blv[BI];
        #pragma unroll
        for (int i = 0; i < BI; ++i) {
            int idx = tid + 256 * i;
            int col = idx >> 2, ch = idx & 3;
            bhv[i] = *(const s16x8*)(Bt_hi + (size_t)(bn + col) * K + k0 + ch * 8);
            blv[i] = *(const s16x8*)(Bt_lo + (size_t)(bn + col) * K + k0 + ch * 8);
        }
        __syncthreads();
        #pragma unroll
        for (int i = 0; i < 4; ++i) {
            int idx = tid + 256 * i;
            int row = idx >> 3, c4 = idx & 7;
            float vs[4] = {av[i].x, av[i].y, av[i].z, av[i].w};
            unsigned short h[4], l[4];
            #pragma unroll
            for (int j = 0; j < 4; ++j) {
                h[j] = f2bf(vs[j]);
                l[j] = f2bf(vs[j] - bf2f(h[j]));
            }
            *(s16x4*)&sAh[row][c4 * 4] = (s16x4){(short)h[0], (short)h[1], (short)h[2], (short)h[3]};
            *(s16x4*)&sAl[row][c4 * 4] = (s16x4){(short)l[0], (short)l[1], (short)l[2], (short)l[3]};
        }
        #pragma unroll
        for (int i = 0; i < BI; ++i) {
            int idx = tid + 256 * i;
            int col = idx >> 2, ch = idx & 3;
            *(s16x8*)&sBh[col][ch * 8] = bhv[i];
            *(s16x8*)&sBl[col][ch * 8] = blv[i];
        }
        __syncthreads();
        // fragment loads + 3-term MFMA
        s16x8 afh[4], afl[4], bfh[CB], bfl[CB];
        #pragma unroll
        for (int rb = 0; rb < 4; ++rb) {
            int row = wr * 64 + rb * 16 + lr;
            afh[rb] = *(const s16x8*)&sAh[row][lk * 8];
            afl[rb] = *(const s16x8*)&sAl[row][lk * 8];
        }
        #pragma unroll
        for (int cb = 0; cb < CB; ++cb) {
            int col = wc * (BN / 2) + cb * 16 + lr;
            bfh[cb] = *(const s16x8*)&sBh[col][lk * 8];
            bfl[cb] = *(const s16x8*)&sBl[col][lk * 8];
        }
        #pragma unroll
        for (int rb = 0; rb < 4; ++rb)
            #pragma unroll
            for (int cb = 0; cb < CB; ++cb) {
                acc[rb][cb] = __builtin_amdgcn_mfma_f32_16x16x32_bf16(afh[rb], bfh[cb], acc[rb][cb], 0, 0, 0);
                acc[rb][cb] = __builtin_amdgcn_mfma_f32_16x16x32_bf16(afh[rb], bfl[cb], acc[rb][cb], 0, 0, 0);
                acc[rb][cb] = __builtin_amdgcn_mfma_f32_16x16x32_bf16(afl[rb], bfh[cb], acc[rb][cb], 0, 0, 0);
            }
    }
    // epilogue: C/D layout col=lane&15, row=(lane>>4)*4+r  [m89-verified]
    #pragma unroll
    for (int rb = 0; rb < 4; ++rb)
        #pragma unroll
        for (int cb = 0; cb < CB; ++cb)
            #pragma unroll
            for (int r = 0; r < 4; ++r) {
                int row = bm + wr * 64 + rb * 16 + lk * 4 + r;
                int col = bn + wc * (BN / 2) + cb * 16 + lr;
                if (row < M) {
                    float v = acc[rb][cb][r];
                    C[(size_t)row * N + col] = v;
                    if (Ch) Ch[(size_t)row * N + col] = (_Float16)v;
                }
            }
}

// ---------------------------------------------------------------------------
// s[n,h] = sum_c h[n,h,c]*a_src[h,c]; d likewise. One wave per node.
template<int H>
__global__ __launch_bounds__(256)
void sd_k(const float* __restrict__ hfeat, const float* __restrict__ a_src,
          const float* __restrict__ a_dst, float* __restrict__ s,
          float* __restrict__ d, int n) {
    const int lane = threadIdx.x & 63;
    const int node = blockIdx.x * 4 + (threadIdx.x >> 6);
    if (node >= n) return;
    const float* row = hfeat + (size_t)node * (H * 64);
    #pragma unroll
    for (int h = 0; h < H; ++h) {
        float f = row[h * 64 + lane];
        float vs = f * a_src[h * 64 + lane];
        float vd = f * a_dst[h * 64 + lane];
        #pragma unroll
        for (int m = 32; m; m >>= 1) {
            vs += __shfl_xor(vs, m);
            vd += __shfl_xor(vd, m);
        }
        if (lane == 0) { s[node * H + h] = vs; d[node * H + h] = vd; }
    }
}

// ---------------------------------------------------------------------------
__device__ __forceinline__ float leaky(float e) { return (e > 0.f) ? e : 0.2f * e; }

__device__ __forceinline__ float sel4(const float v[4], int idx) {
    float r = v[0];
    r = (idx == 1) ? v[1] : r;
    r = (idx == 2) ? v[2] : r;
    r = (idx == 3) ? v[3] : r;
    return r;
}

__device__ __forceinline__ void osm_upd(float& m, float& sm, float e) {
    float nm = fmaxf(m, e);
    sm = sm * __expf(m - nm) + __expf(e - nm);
    m = nm;
}

// GAT attention + aggregation, one wave per dst node. out = relu(agg + bias).
// EB path (2 passes, no max subtraction -- logits bounded ~O(10) here, and
// exp(e)/sum == exp(e-max)/sum mathematically):
//   pass1: ex = exp(leaky(s[src]+d[dst])) -> ebuf; wave-reduce denom
//   pass2: half8 row gather (16B/lane), multi-edge in flight; inv in epilogue
template<int H, bool EB>
__global__ __launch_bounds__(256)
void agg_k(const float* __restrict__ hfeat, const _Float16* __restrict__ hhalf,
           const float* __restrict__ s, const float* __restrict__ d,
           const float* __restrict__ bias, const int* __restrict__ rowptr,
           const int* __restrict__ csr_src, float* __restrict__ ebuf,
           float* __restrict__ out, int n) {
    const int lane = threadIdx.x & 63;
    const int node = blockIdx.x * 4 + (threadIdx.x >> 6);
    if (node >= n) return;
    const int beg = rowptr[node];
    const int end = rowptr[node + 1];
    float dh[H], dn[H], inv[H];
    #pragma unroll
    for (int h = 0; h < H; ++h) {
        dh[h] = d[node * H + h];
        dn[h] = 0.f;
    }

    if constexpr (EB) {
        // pass 1: ex = exp(leaky(s[src]+d[dst])) -> ebuf; accumulate denom
        for (int i = beg + lane; i < end; i += 64) {
            int sidx = csr_src[i];
            if constexpr (H == 4) {
                float4 sv = *(const float4*)(s + (size_t)sidx * 4);
                float4 ex;
                ex.x = __expf(leaky(sv.x + dh[0]));
                ex.y = __expf(leaky(sv.y + dh[1]));
                ex.z = __expf(leaky(sv.z + dh[2]));
                ex.w = __expf(leaky(sv.w + dh[3]));
                *(float4*)(ebuf + (size_t)i * 4) = ex;
                dn[0] += ex.x; dn[1] += ex.y; dn[2] += ex.z; dn[3] += ex.w;
            } else {
                float ex = __expf(leaky(s[sidx] + dh[0]));
                ebuf[i] = ex;
                dn[0] += ex;
            }
        }
        #pragma unroll
        for (int h = 0; h < H; ++h) {
            #pragma unroll
            for (int m = 32; m; m >>= 1) dn[h] += __shfl_xor(dn[h], m);
            inv[h] = 1.f / (dn[h] + 1e-16f);
        }

        if constexpr (H == 4) {
            // 32 lanes per row (half8 = 16B/lane), 2 edges/instr, 8 in flight
            const half8* H8 = (const half8*)hhalf;   // 32 half8 per row
            const int sub = lane >> 5;               // 0/1: which edge of pair
            const int c8 = lane & 31;                // channel octet 0..31
            const int head = c8 >> 3;
            const float invh = sel4(inv, head);
            float acc[8] = {};
            int i = beg;
            for (; i + 7 < end; i += 8) {
                int e0 = i + sub, e1 = i + 2 + sub, e2 = i + 4 + sub, e3 = i + 6 + sub;
                int s0 = csr_src[e0], s1 = csr_src[e1];
                int s2 = csr_src[e2], s3 = csr_src[e3];
                float x0 = ebuf[(size_t)e0 * 4 + head];
                float x1 = ebuf[(size_t)e1 * 4 + head];
                float x2 = ebuf[(size_t)e2 * 4 + head];
                float x3 = ebuf[(size_t)e3 * 4 + head];
                half8 h0 = H8[(size_t)s0 * 32 + c8];
                half8 h1 = H8[(size_t)s1 * 32 + c8];
                half8 h2 = H8[(size_t)s2 * 32 + c8];
                half8 h3 = H8[(size_t)s3 * 32 + c8];
                #pragma unroll
                for (int j = 0; j < 8; ++j)
                    acc[j] += x0 * (float)h0[j] + x1 * (float)h1[j]
                            + x2 * (float)h2[j] + x3 * (float)h3[j];
            }
            for (; i < end; i += 2) {
                int e = i + sub;
                if (e < end) {
                    int s0 = csr_src[e];
                    float x = ebuf[(size_t)e * 4 + head];
                    half8 hh = H8[(size_t)s0 * 32 + c8];
                    #pragma unroll
                    for (int j = 0; j < 8; ++j) acc[j] += x * (float)hh[j];
                }
            }
            #pragma unroll
            for (int j = 0; j < 8; ++j) acc[j] += __shfl_xor(acc[j], 32);
            if (lane < 32) {
                float4 b0 = *(const float4*)(bias + c8 * 8);
                float4 b1 = *(const float4*)(bias + c8 * 8 + 4);
                float4 o0, o1;
                o0.x = fmaxf(acc[0] * invh + b0.x, 0.f);
                o0.y = fmaxf(acc[1] * invh + b0.y, 0.f);
                o0.z = fmaxf(acc[2] * invh + b0.z, 0.f);
                o0.w = fmaxf(acc[3] * invh + b0.w, 0.f);
                o1.x = fmaxf(acc[4] * invh + b1.x, 0.f);
                o1.y = fmaxf(acc[5] * invh + b1.y, 0.f);
                o1.z = fmaxf(acc[6] * invh + b1.z, 0.f);
                o1.w = fmaxf(acc[7] * invh + b1.w, 0.f);
                *(float4*)(out + (size_t)node * 256 + c8 * 8) = o0;
                *(float4*)(out + (size_t)node * 256 + c8 * 8 + 4) = o1;
            }
        } else {
            // 8 lanes per row (half8), 8 edges/instr, 16 in flight
            const half8* H8 = (const half8*)hhalf;   // 8 half8 per row
            const int sub = lane >> 3;               // 0..7
            const int c8 = lane & 7;
            float acc[8] = {};
            int i = beg;
            for (; i + 15 < end; i += 16) {
                int e0 = i + sub, e1 = i + 8 + sub;
                int s0 = csr_src[e0], s1 = csr_src[e1];
                float x0 = ebuf[e0], x1 = ebuf[e1];
                half8 h0 = H8[(size_t)s0 * 8 + c8];
                half8 h1 = H8[(size_t)s1 * 8 + c8];
                #pragma unroll
                for (int j = 0; j < 8; ++j)
                    acc[j] += x0 * (float)h0[j] + x1 * (float)h1[j];
            }
            for (; i < end; i += 8) {
                int e = i + sub;
                if (e < end) {
                    int s0 = csr_src[e];
                    float x = ebuf[e];
                    half8 hh = H8[(size_t)s0 * 8 + c8];
                    #pragma unroll
                    for (int j = 0; j < 8; ++j) acc[j] += x * (float)hh[j];
                }
            }
            #pragma unroll
            for (int m = 8; m <= 32; m <<= 1)
                #pragma unroll
                for (int j = 0; j < 8; ++j) acc[j] += __shfl_xor(acc[j], m);
            if (lane < 8) {
                float4 b0 = *(const float4*)(bias + c8 * 8);
                float4 b1 = *(const float4*)(bias + c8 * 8 + 4);
                float4 o0, o1;
                o0.x = fmaxf(acc[0] * inv[0] + b0.x, 0.f);
                o0.y = fmaxf(acc[1] * inv[0] + b0.y, 0.f);
                o0.z = fmaxf(acc[2] * inv[0] + b0.z, 0.f);
                o0.w = fmaxf(acc[3] * inv[0] + b0.w, 0.f);
                o1.x = fmaxf(acc[4] * inv[0] + b1.x, 0.f);
                o1.y = fmaxf(acc[5] * inv[0] + b1.y, 0.f);
                o1.z = fmaxf(acc[6] * inv[0] + b1.z, 0.f);
                o1.w = fmaxf(acc[7] * inv[0] + b1.w, 0.f);
                *(float4*)(out + (size_t)node * 64 + c8 * 8) = o0;
                *(float4*)(out + (size_t)node * 64 + c8 * 8 + 4) = o1;
            }
        }
    } else {
        // fallback (no ebuf): online softmax + serial recompute, fp32 h
        float mx[H], sm[H];
        #pragma unroll
        for (int h = 0; h < H; ++h) { mx[h] = -3.0e38f; sm[h] = 0.f; }
        for (int i = beg + lane; i < end; i += 64) {
            int sidx = csr_src[i];
            if constexpr (H == 4) {
                float4 sv = *(const float4*)(s + (size_t)sidx * 4);
                osm_upd(mx[0], sm[0], leaky(sv.x + dh[0]));
                osm_upd(mx[1], sm[1], leaky(sv.y + dh[1]));
                osm_upd(mx[2], sm[2], leaky(sv.z + dh[2]));
                osm_upd(mx[3], sm[3], leaky(sv.w + dh[3]));
            } else {
                osm_upd(mx[0], sm[0], leaky(s[sidx] + dh[0]));
            }
        }
        #pragma unroll
        for (int h = 0; h < H; ++h) {
            #pragma unroll
            for (int dd = 32; dd; dd >>= 1) {
                float om = __shfl_xor(mx[h], dd);
                float os = __shfl_xor(sm[h], dd);
                float nm = fmaxf(mx[h], om);
                sm[h] = sm[h] * __expf(mx[h] - nm) + os * __expf(om - nm);
                mx[h] = nm;
            }
            inv[h] = 1.f / (sm[h] + 1e-16f);
        }
        if constexpr (H == 4) {
            const int head = lane >> 4;
            const float invh = sel4(inv, head);
            const float mxh = sel4(mx, head);
            const float dhh = sel4(dh, head);
            const float4* H4 = (const float4*)hfeat;
            float4 acc = {0.f, 0.f, 0.f, 0.f};
            for (int i = beg; i < end; ++i) {
                int s0 = csr_src[i];
                float al0 = __expf(leaky(s[(size_t)s0 * 4 + head] + dhh) - mxh) * invh;
                float4 h0 = H4[(size_t)s0 * 64 + lane];
                acc.x += al0 * h0.x; acc.y += al0 * h0.y;
                acc.z += al0 * h0.z; acc.w += al0 * h0.w;
            }
            float4 bv = ((const float4*)bias)[lane];
            float4 o;
            o.x = fmaxf(acc.x + bv.x, 0.f); o.y = fmaxf(acc.y + bv.y, 0.f);
            o.z = fmaxf(acc.z + bv.z, 0.f); o.w = fmaxf(acc.w + bv.w, 0.f);
            ((float4*)out)[(size_t)node * 64 + lane] = o;
        } else {
            float acc = 0.f;
            for (int i = beg; i < end; ++i) {
                int s0 = csr_src[i];
                float a0 = __expf(leaky(s[s0] + dh[0]) - mx[0]) * inv[0];
                acc += a0 * hfeat[(size_t)s0 * 64 + lane];
            }
            float v = acc + bias[lane];
            out[(size_t)node * 64 + lane] = fmaxf(v, 0.f);
        }
    }
}

// ---------------------------------------------------------------------------
// Fused FF: out = softmax(relu(in@Wf1+bf1)@Wf2+bf2). Grid-stride; weights in
// LDS once per block. xrow/yrow are wave-private (no cross-wave barrier).
__global__ __launch_bounds__(256)
void ff_k(const float* __restrict__ in, const float* __restrict__ Wf1,
          const float* __restrict__ bf1, const float* __restrict__ Wf2,
          const float* __restrict__ bf2, float* __restrict__ out, int n) {
    __shared__ float w1[64 * 64];
    __shared__ float w2[64 * 64];
    __shared__ float xrow[4][64];
    __shared__ float yrow[4][64];
    const int tid = threadIdx.x;
    for (int i = tid; i < 64 * 64; i += 256) { w1[i] = Wf1[i]; w2[i] = Wf2[i]; }
    __syncthreads();
    const int wv = tid >> 6;
    const int lane = tid & 63;
    const float B1 = bf1[lane], B2 = bf2[lane];
    const int nblk = (n + 3) / 4;
    for (int nb = blockIdx.x; nb < nblk; nb += gridDim.x) {
        int node = nb * 4 + wv;
        int nd = node < n ? node : (n - 1);
        float x = in[(size_t)nd * 64 + lane];
        xrow[wv][lane] = x;
        float y = B1;
        #pragma unroll 8
        for (int k = 0; k < 64; ++k) y += xrow[wv][k] * w1[k * 64 + lane];
        y = fmaxf(y, 0.f);
        yrow[wv][lane] = y;
        float z = B2;
        #pragma unroll 8
        for (int k = 0; k < 64; ++k) z += yrow[wv][k] * w2[k * 64 + lane];
        float m = z;
        #pragma unroll
        for (int dd = 32; dd; dd >>= 1) m = fmaxf(m, __shfl_xor(m, dd));
        float ex = __expf(z - m);
        float sum = ex;
        #pragma unroll
        for (int dd = 32; dd; dd >>= 1) sum += __shfl_xor(sum, dd);
        if (node < n) out[(size_t)node * 64 + lane] = ex / sum;
    }
}

// ---------------------------------------------------------------------------
extern "C" void kernel_launch(void* const* d_in, const int* in_sizes, int n_in,
                              void* d_out, int out_size, void* d_ws, size_t ws_size,
                              hipStream_t stream) {
    const float* x      = (const float*)d_in[0];
    const void*  ei     = d_in[1];
    const float* W1     = (const float*)d_in[2];
    const float* a_src1 = (const float*)d_in[3];
    const float* a_dst1 = (const float*)d_in[4];
    const float* b1     = (const float*)d_in[5];
    const float* W2     = (const float*)d_in[6];
    const float* a_src2 = (const float*)d_in[7];
    const float* a_dst2 = (const float*)d_in[8];
    const float* b2     = (const float*)d_in[9];
    const float* Wf1    = (const float*)d_in[10];
    const float* bf1    = (const float*)d_in[11];
    const float* Wf2    = (const float*)d_in[12];
    const float* bf2    = (const float*)d_in[13];
    float* outp = (float*)d_out;

    // workspace carve-up (256B aligned)
    char* ws = (char*)d_ws;
    size_t off = 0;
    auto take = [&](size_t bytes) -> char* {
        char* p = ws + off;
        off += (bytes + 255) & ~(size_t)255;
        return p;
    };
    int*   flag   = (int*)take(4);
    int*   count  = (int*)take((size_t)NNODES * 4);
    int*   fill   = (int*)take((size_t)NNODES * 4);
    int*   rowptr = (int*)take((size_t)(NNODES + 1) * 4);
    int*   bsum   = (int*)take(64 * 4);
    int*   bpre   = (int*)take(64 * 4);
    int*   csr    = (int*)take((size_t)ETOT * 4);
    unsigned short* w1t_hi = (unsigned short*)take((size_t)256 * 256 * 2);
    unsigned short* w1t_lo = (unsigned short*)take((size_t)256 * 256 * 2);
    unsigned short* w2t_hi = (unsigned short*)take((size_t)64 * 256 * 2);
    unsigned short* w2t_lo = (unsigned short*)take((size_t)64 * 256 * 2);
    float* h1     = (float*)take((size_t)NNODES * 256 * 4);
    float* agg1   = (float*)take((size_t)NNODES * 256 * 4);
    float* s1     = (float*)take((size_t)NNODES * HEADS * 4);
    float* d1     = (float*)take((size_t)NNODES * HEADS * 4);
    float* ebuf   = (float*)take((size_t)ETOT * HEADS * 4);
    _Float16* h1h = (_Float16*)take((size_t)NNODES * 256 * 2);
    const bool eb_ok = (off <= ws_size);
    // reuse dead buffers for layer 2
    float*    h2   = h1;
    float*    s2   = s1;
    float*    d2   = d1;
    float*    agg2 = agg1;
    _Float16* h2h  = h1h;

    // CSR build (shared by both GAT layers)
    detect_k<<<1, 128, 0, stream>>>((const unsigned*)ei, flag);
    hipMemsetAsync(count, 0, (size_t)NNODES * 4, stream);
    hipMemsetAsync(fill, 0, (size_t)NNODES * 4, stream);
    const int eblocks = (ETOT + 255) / 256;
    hist_k<<<eblocks, 256, 0, stream>>>(ei, flag, count);
    const int sblocks = (NNODES + 1023) / 1024;  // 49
    scan1_k<<<sblocks, 1024, 0, stream>>>(count, rowptr, bsum, NNODES);
    scan2_k<<<1, 64, 0, stream>>>(bsum, bpre, sblocks, rowptr, NNODES);
    scan3_k<<<sblocks, 1024, 0, stream>>>(rowptr, bpre, NNODES);
    scatter_k<<<eblocks, 256, 0, stream>>>(ei, flag, rowptr, fill, csr);

    // Weight pre-convert (tiny)
    convw_k<<<(256 * 256) / 256, 256, 0, stream>>>(W1, w1t_hi, w1t_lo, 256, 256);
    convw_k<<<(256 * 64) / 256, 256, 0, stream>>>(W2, w2t_hi, w2t_lo, 256, 64);

    const int nodeblocks = NNODES / 4;  // 12500
    const int mblocks = (NNODES + 127) / 128;  // 391
    const dim3 gg1(2, mblocks);   // N=256, BN=128
    const dim3 gg2(1, mblocks);   // N=64,  BN=64

    // Layer 1
    gemm_mfma_k<128><<<gg1, 256, 0, stream>>>(x, w1t_hi, w1t_lo, h1,
                                              eb_ok ? h1h : nullptr, NNODES, 256, 256);
    sd_k<HEADS><<<nodeblocks, 256, 0, stream>>>(h1, a_src1, a_dst1, s1, d1, NNODES);
    if (eb_ok)
        agg_k<HEADS, true><<<nodeblocks, 256, 0, stream>>>(h1, h1h, s1, d1, b1, rowptr, csr, ebuf, agg1, NNODES);
    else
        agg_k<HEADS, false><<<nodeblocks, 256, 0, stream>>>(h1, h1h, s1, d1, b1, rowptr, csr, ebuf, agg1, NNODES);

    // Layer 2
    gemm_mfma_k<64><<<gg2, 256, 0, stream>>>(agg1, w2t_hi, w2t_lo, h2,
                                             eb_ok ? h2h : nullptr, NNODES, 64, 256);
    sd_k<1><<<nodeblocks, 256, 0, stream>>>(h2, a_src2, a_dst2, s2, d2, NNODES);
    if (eb_ok)
        agg_k<1, true><<<nodeblocks, 256, 0, stream>>>(h2, h2h, s2, d2, b2, rowptr, csr, ebuf, agg2, NNODES);
    else
        agg_k<1, false><<<nodeblocks, 256, 0, stream>>>(h2, h2h, s2, d2, b2, rowptr, csr, ebuf, agg2, NNODES);

    // FF + softmax
    ff_k<<<1024, 256, 0, stream>>>(agg2, Wf1, bf1, Wf2, bf2, outp, NNODES);
}